// Round 8
// baseline (416.250 us; speedup 1.0000x reference)
//
#include <hip/hip_runtime.h>
#include <math.h>

#define NRAYS 16384
#define NC    64
#define NF    128
#define NZ    192   // NC + NF
#define H     64

typedef __attribute__((ext_vector_type(8))) short bf16x8;  // 8 bf16 (4 VGPRs)
typedef __attribute__((ext_vector_type(4))) float f32x4;   // MFMA C/D
typedef __attribute__((ext_vector_type(4))) int   i32x4;
typedef __attribute__((ext_vector_type(2))) float f32x2;   // packed-f32 (head only)

// Packed dual-f32 fma — bit-identical per element to fmaf; lowers to
// v_pk_fma_f32. Used ONLY in the head (R18 lesson: blanket f32x2 costs
// +8 VGPR -> occupancy cliff; head-only P2[8] is register-neutral vs P[16]).
__device__ __forceinline__ f32x2 pk_fma2(f32x2 a, f32x2 b, f32x2 c) {
  return __builtin_elementwise_fma(a, b, c);
}

// One-instruction pack: result.hi16 = a[31:16], result.lo16 = b[31:16].
// v_perm_b32 byte-select (sel bytes 0-3 pick from src1, 4-7 from src0);
// bit-identical to (b>>16)|(a&0xFFFF0000).
__device__ __forceinline__ int pack_hi16(unsigned a, unsigned b) {
  return (int)__builtin_amdgcn_perm(a, b, 0x07060302u);
}

__device__ __forceinline__ float wave_incl_scan(float v, int lane) {
#pragma unroll
  for (int off = 1; off < 64; off <<= 1) {
    float n = __shfl_up(v, off);
    v = (lane >= off) ? v + n : v;
  }
  return v;
}

__device__ __forceinline__ float wave_incl_max_scan(float v, int lane) {
#pragma unroll
  for (int off = 1; off < 64; off <<= 1) {
    float n = __shfl_up(v, off);
    v = (lane >= off) ? fmaxf(v, n) : v;
  }
  return v;
}

__device__ __forceinline__ float wave_sum(float v) {
#pragma unroll
  for (int off = 32; off > 0; off >>= 1) v += __shfl_xor(v, off);
  return v;
}

// fp32 -> bf16 hi + bf16 lo (truncation split; 3-term MFMA has rel err ~2^-15).
__device__ __forceinline__ void split_bf16(float f, short& hi, short& lo) {
  unsigned u = __float_as_uint(f);
  hi = (short)(u >> 16);
  float rem = f - __uint_as_float(u & 0xFFFF0000u);   // exact
  lo = (short)(__float_as_uint(rem) >> 16);
}

// Fast sigmoid: OUTPUT-ONLY paths (never feeds the coarse pdf->cdf->sampling
// chain, which must stay bit-stable: bin flips cost O(0.03) absmax).
__device__ __forceinline__ float fsig(float x) {
  return __builtin_amdgcn_rcpf(1.f + __expf(-x));
}

// Layer-1 weights in LDS — read per-batch via a/b precompute.
struct __align__(16) WLds {
  float W1b[H][4];   // {w1[0][k], w1[1][k], w1[2][k], b1[k]}
};

// Register-resident w2 fragments (hi/lo split) + head bias.
struct MfmaW {
  bf16x8 Bhi[2][4], Blo[2][4];  // w2 [kt][jt]
  float  hbown;                 // head bias for this lane's c = n16&3
};

__device__ __forceinline__ void load_mfma_weights(
    int lane,
    const float* __restrict__ w2,
    const float* __restrict__ br, const float* __restrict__ bd,
    MfmaW& M)
{
  const int quad = lane >> 4, n16 = lane & 15;
#pragma unroll
  for (int kt = 0; kt < 2; ++kt) {
#pragma unroll
    for (int jt = 0; jt < 4; ++jt) {
#pragma unroll
      for (int j = 0; j < 8; ++j) {
        const int k = kt*32 + quad*8 + j;
        short hi, lo;
        split_bf16(w2[k*H + jt*16 + n16], hi, lo);
        M.Bhi[kt][jt][j] = hi; M.Blo[kt][jt][j] = lo;
      }
    }
  }
  const int c = n16 & 3;
  M.hbown = (c == 0) ? br[0] : (c == 1) ? br[1] : (c == 2) ? br[2] : bd[0];
}

// ONE mt sub-batch (16 samples). Layer1: h1_k = relu(a_k + z*b_k), a/b
// quad-broadcast from LDS; bf16 hi/lo packed via v_perm (bit-identical).
// Layer2: split-bf16 MFMA. Head: pk_fma P2[8] + halving butterfly
// (bit-identical element order to the scalar P[16] form, verified R18).
__device__ __forceinline__ void mlp_mfma_batch_one(
    int mt, int lane, const float2* __restrict__ AB,
    const float* __restrict__ zsrc, const MfmaW& M,
    const float (*__restrict__ sHW)[4], const float* __restrict__ sB2,
    float* __restrict__ R)
{
  const int quad = lane >> 4, n16 = lane & 15;
  const float z = zsrc[mt*16 + n16];
  f32x4 C[4];
#pragma unroll
  for (int jt = 0; jt < 4; ++jt) {
    const float b2v = sB2[jt*16 + n16];
    C[jt] = (f32x4){b2v, b2v, b2v, b2v};
  }
#pragma unroll
  for (int kt = 0; kt < 2; ++kt) {
    const float4* abp = (const float4*)(AB + kt*32 + quad*8);
    i32x4 hip, lop;
#pragma unroll
    for (int j2 = 0; j2 < 4; ++j2) {
      const float4 p = abp[j2];                 // {a0,b0,a1,b1}
      const float h0 = fmaxf(fmaf(z, p.y, p.x), 0.f);
      const float h1 = fmaxf(fmaf(z, p.w, p.z), 0.f);
      const unsigned u0 = __float_as_uint(h0), u1 = __float_as_uint(h1);
      hip[j2] = pack_hi16(u1, u0);
      const float r0 = h0 - __uint_as_float(u0 & 0xFFFF0000u);
      const float r1 = h1 - __uint_as_float(u1 & 0xFFFF0000u);
      lop[j2] = pack_hi16(__float_as_uint(r1), __float_as_uint(r0));
    }
    union { i32x4 i; bf16x8 h; } uh, ul;
    uh.i = hip; ul.i = lop;
#pragma unroll
    for (int jt = 0; jt < 4; ++jt) {
      C[jt] = __builtin_amdgcn_mfma_f32_16x16x32_bf16(uh.h, M.Bhi[kt][jt], C[jt], 0, 0, 0);
      C[jt] = __builtin_amdgcn_mfma_f32_16x16x32_bf16(ul.h, M.Bhi[kt][jt], C[jt], 0, 0, 0);
      C[jt] = __builtin_amdgcn_mfma_f32_16x16x32_bf16(uh.h, M.Blo[kt][jt], C[jt], 0, 0, 0);
    }
  }
  // ---- head: P2[r*2+{0,1}] = {c0,c1},{c2,c3} partials (pk_fma) ----
  f32x2 P2[8];
#pragma unroll
  for (int i = 0; i < 8; ++i) P2[i] = (f32x2){0.f, 0.f};
#pragma unroll
  for (int jt = 0; jt < 4; ++jt) {
    const float4 hwv = *(const float4*)(&sHW[jt*16 + n16][0]);
    const f32x2 hwA = {hwv.x, hwv.y}, hwB = {hwv.z, hwv.w};
#pragma unroll
    for (int r = 0; r < 4; ++r) {
      const float h2v = fmaxf(C[jt][r], 0.f);
      const f32x2 hh = {h2v, h2v};
      P2[r*2+0] = pk_fma2(hh, hwA, P2[r*2+0]);
      P2[r*2+1] = pk_fma2(hh, hwB, P2[r*2+1]);
    }
  }
  // halving reduce across 16 lanes; P[2s]=P2[s].x, P[2s+1]=P2[s].y
  const bool b0 = (n16 & 1), b1 = (n16 & 2), b2_ = (n16 & 4), b3 = (n16 & 8);
  float Q[8];
#pragma unroll
  for (int s = 0; s < 8; ++s) {
    const float give = b0 ? P2[s].x : P2[s].y;
    const float keep = b0 ? P2[s].y : P2[s].x;
    Q[s] = keep + __shfl_xor(give, 1);
  }
  float U[4];
#pragma unroll
  for (int t = 0; t < 4; ++t) {
    const float give = b1 ? Q[2*t] : Q[2*t+1];
    const float keep = b1 ? Q[2*t+1] : Q[2*t];
    U[t] = keep + __shfl_xor(give, 2);
  }
  float V[2];
#pragma unroll
  for (int u = 0; u < 2; ++u) {
    const float give = b2_ ? U[2*u] : U[2*u+1];
    const float keep = b2_ ? U[2*u+1] : U[2*u];
    V[u] = keep + __shfl_xor(give, 4);
  }
  {
    const float give = b3 ? V[0] : V[1];
    const float keep = b3 ? V[1] : V[0];
    const float total = keep + __shfl_xor(give, 8);
    R[mt*64 + lane] = total + M.hbown;   // coalesced: addr = sample*4 + c
  }
}

// Full 64-sample batch (4 mt's on one wave) — used by kernel 2 and the
// coarse pass. Same per-sample code path as batch_one (b2q array removed:
// sB2 re-read per mt frees 4 persistent VGPRs; values identical).
__device__ __forceinline__ void mlp_mfma_batch(
    int lane, const float2* __restrict__ AB,
    const float* __restrict__ zsrc, const MfmaW& M,
    const float (*__restrict__ sHW)[4], const float* __restrict__ sB2,
    float* __restrict__ R)
{
#pragma unroll 1   // rolled: prevents register blow-up (R5/R6 lesson)
  for (int mt = 0; mt < 4; ++mt)
    mlp_mfma_batch_one(mt, lane, AB, zsrc, M, sHW, sB2, R);
  __builtin_amdgcn_wave_barrier();     // R complete before readback
}

// Coarse pass for one ray, ONE wave, wave-private LDS scratch.
// NOTE: alpha/trans keep ACCURATE expf — they feed the pdf->cdf->inverse-CDF
// chain; perturbing them can flip binary-search bins (absmax blowup).
__device__ __forceinline__ void coarse_pass(
    int ray, int lane,
    const float* __restrict__ origins, const float* __restrict__ dirs,
    const float* __restrict__ nearp, const float* __restrict__ farp,
    const float* __restrict__ bkgd,
    const WLds& W, const MfmaW& M,
    const float (*__restrict__ sHW)[4], const float* __restrict__ sB2,
    float* __restrict__ R, float2* __restrict__ sAB,
    float* __restrict__ sT, float* __restrict__ sBins,
    float* __restrict__ sCdf, float* __restrict__ sZs,
    float* __restrict__ zdst, bool emit, float* __restrict__ out)
{
  const float nearv = nearp[ray];
  const float farv  = farp[ray];
  const float ox = origins[ray*3+0], oy = origins[ray*3+1], oz = origins[ray*3+2];
  const float dx = dirs[ray*3+0],    dy = dirs[ray*3+1],    dz = dirs[ray*3+2];

  {
    const float4 wv = *(const float4*)(&W.W1b[lane][0]);
    const float a = fmaf(ox, wv.x, fmaf(oy, wv.y, fmaf(oz, wv.z, wv.w)));
    const float b = fmaf(dx, wv.x, fmaf(dy, wv.y, dz * wv.z));
    sAB[lane] = (float2){a, b};
  }

  const float u_i  = (float)lane / 63.0f;
  const float u_n  = (float)(lane + 1) / 63.0f;
  const float tv    = nearv * (1.f - u_i) + farv * u_i;
  const float tnext = nearv * (1.f - u_n) + farv * u_n;

  sT[lane] = tv;
  if (lane < NC-1) sBins[lane] = 0.5f * (tv + tnext);
  zdst[lane] = 0.f; zdst[lane+64] = 0.f; zdst[lane+128] = 0.f;
  __builtin_amdgcn_wave_barrier();     // sT + sAB ready for the batch

  mlp_mfma_batch(lane, sAB, sT, M, sHW, sB2, R);
  const float4 rr = *(const float4*)(&R[lane*4]);
  const float rgb0 = fsig(rr.x), rgb1 = fsig(rr.y), rgb2 = fsig(rr.z);
  const float dens = fmaxf(rr.w, 0.f);

  const float dnorm = sqrtf(dx*dx + dy*dy + dz*dz);
  const float tdist = (lane == NC-1) ? 1e10f : (tnext - tv);
  const float dd    = fminf(dens * (tdist * dnorm), 1e4f);
  const float incl  = wave_incl_scan(dd, lane);
  const float excl  = incl - dd;
  const float alpha = 1.f - expf(-dd);     // pdf-critical: accurate
  const float trans = expf(-excl);         // pdf-critical: accurate
  const float w     = alpha * trans;

  if (emit) {
    const float near0 = nearp[0], far0 = farp[0];
    const float t0v   = near0 * (1.f - u_i) + far0 * u_i;
    const float s_w   = wave_sum(w);
    const float s_wt  = wave_sum(w * tv);
    const float s_c0  = wave_sum(w * rgb0);
    const float s_c1  = wave_sum(w * rgb1);
    const float s_c2  = wave_sum(w * rgb2);
    const float s_wt0 = wave_sum(w * t0v);
    if (lane == 0) {
      const float bk0 = bkgd[0], bk1 = bkgd[1], bk2 = bkgd[2];
      const float o0x = origins[0], o0y = origins[1], o0z = origins[2];
      const float d0x = dirs[0],    d0y = dirs[1],    d0z = dirs[2];
      const float oma = 1.f - s_w;
      float* o = out + (size_t)ray * 16;
      o[0] = s_c0 + bk0 * oma;
      o[1] = s_c1 + bk1 * oma;
      o[2] = s_c2 + bk2 * oma;
      o[3] = s_wt;
      o[4] = s_w;
      o[5] = s_w * o0x + s_wt0 * d0x;
      o[6] = s_w * o0y + s_wt0 * d0y;
      o[7] = s_w * o0z + s_wt0 * d0z;
    }
  }

  // ---- PDF -> CDF (62 weights = w[1..62]) ----
  const float wnext = __shfl_down(w, 1);
  const float pw = (lane < NC-2) ? wnext : 0.f;
  const float ws_sum = wave_sum(pw);
  const float pad = fmaxf(1e-5f - ws_sum, 0.f);
  const float wsp = ws_sum + pad;
  const float pdf = (lane < NC-2) ? (pw + pad * (1.f/62.f)) / wsp : 0.f;
  float ip  = wave_incl_scan(pdf, lane);
  ip = wave_incl_max_scan(ip, lane);       // exact monotone
  if (lane < 61)  sCdf[lane+1] = fminf(ip, 1.f);
  if (lane == 61) sCdf[0]  = 0.f;
  if (lane == 62) sCdf[62] = 1.f;
  __builtin_amdgcn_wave_barrier();

  // ---- inverse-CDF: 128 samples, 2 per lane ----
  const float ustep = (1.0f - 1.1920929e-07f) / 127.0f;
#pragma unroll
  for (int r = 0; r < 2; ++r) {
    const int k = lane + 64*r;
    const float u = k * ustep;
    int lo = 0, hi = 61;
    while (lo < hi) {
      const int mid = (lo + hi + 1) >> 1;
      if (sCdf[mid] <= u) lo = mid; else hi = mid - 1;
    }
    const int J = lo;
    const float cg0 = sCdf[J],  cg1 = sCdf[J+1];
    const float bg0 = sBins[J], bg1 = sBins[J+1];
    const float denom = cg1 - cg0;
    const float num   = u - cg0;
    float tt;
    if (denom > 0.f) tt = fminf(fmaxf(num / denom, 0.f), 1.f);
    else             tt = (num > 0.f) ? 1.f : 0.f;
    sZs[k] = fmaf(tt, bg1 - bg0, bg0);
  }
  __builtin_amdgcn_wave_barrier();

  // ---- stable rank merge of sorted t (64) and z (128) into zdst (192) ----
  {
    int l = 0, r = NF;
    while (l < r) { const int m = (l + r) >> 1; if (sZs[m] < tv) l = m + 1; else r = m; }
    zdst[lane + l] = tv;
  }
#pragma unroll
  for (int r2 = 0; r2 < 2; ++r2) {
    const int k = lane + 64*r2;
    const float z = sZs[k];
    int l = 0, r = NC;
    while (l < r) { const int m = (l + r) >> 1; if (sT[m] <= z) l = m + 1; else r = m; }
    zdst[k + l] = z;
  }
  __builtin_amdgcn_wave_barrier();
}

// -------- Kernel 1: ONE block, 4 waves (R17 structure, verified). MLP is
// 4-wave (wave wv computes mt = wv); the serial tail runs on wave 0. --------
__global__ __launch_bounds__(256) void nerf_z0_kernel(
    const float* __restrict__ origins, const float* __restrict__ dirs,
    const float* __restrict__ nearp, const float* __restrict__ farp,
    const float* __restrict__ w1c, const float* __restrict__ b1c,
    const float* __restrict__ w2c, const float* __restrict__ b2c,
    const float* __restrict__ wrc, const float* __restrict__ brc,
    const float* __restrict__ wdc, const float* __restrict__ bdc,
    float* __restrict__ gz0)
{
  __shared__ WLds sW;
  __shared__ float sHW[H][4];
  __shared__ float sB2[H];
  __shared__ float sT[NC], sBins[NC], sCdf[NC], sZs[NF], sZv0[NZ];
  __shared__ float sR[256];
  __shared__ __align__(16) float2 sAB[H];

  const int tid  = threadIdx.x;
  const int wv   = tid >> 6;
  const int lane = tid & 63;

  if (tid < 64) {
    const int k = tid;
    sW.W1b[k][0] = w1c[0*H + k];
    sW.W1b[k][1] = w1c[1*H + k];
    sW.W1b[k][2] = w1c[2*H + k];
    sW.W1b[k][3] = b1c[k];
    sHW[k][0] = wrc[k*3 + 0];
    sHW[k][1] = wrc[k*3 + 1];
    sHW[k][2] = wrc[k*3 + 2];
    sHW[k][3] = wdc[k];
    sB2[k]    = b2c[k];
  }

  MfmaW Mc;                         // every wave needs the fragments
  load_mfma_weights(lane, w2c, brc, bdc, Mc);
  __syncthreads();                  // #1: tables visible to all waves

  const float nearv = nearp[0];
  const float farv  = farp[0];

  // ---- geometry (wave 0; identical formulas to coarse_pass) ----
  if (wv == 0) {
    const float ox = origins[0], oy = origins[1], oz = origins[2];
    const float dx = dirs[0],    dy = dirs[1],    dz = dirs[2];
    const float4 wvv = *(const float4*)(&sW.W1b[lane][0]);
    const float a = fmaf(ox, wvv.x, fmaf(oy, wvv.y, fmaf(oz, wvv.z, wvv.w)));
    const float b = fmaf(dx, wvv.x, fmaf(dy, wvv.y, dz * wvv.z));
    sAB[lane] = (float2){a, b};

    const float u_i  = (float)lane / 63.0f;
    const float u_n  = (float)(lane + 1) / 63.0f;
    const float tv    = nearv * (1.f - u_i) + farv * u_i;
    const float tnext = nearv * (1.f - u_n) + farv * u_n;
    sT[lane] = tv;
    if (lane < NC-1) sBins[lane] = 0.5f * (tv + tnext);
    sZv0[lane] = 0.f; sZv0[lane+64] = 0.f; sZv0[lane+128] = 0.f;
  }
  __syncthreads();                  // #2: sAB/sT ready for all waves

  // ---- 4-wave MLP, wave wv does mt = wv ----
  mlp_mfma_batch_one(wv, lane, sAB, sT, Mc, sHW, sB2, sR);
  __syncthreads();                  // #3: sR complete

  // ---- serial tail: wave 0 only (verified R15 tail, emit=false) ----
  if (wv == 0) {
    const float dx = dirs[0], dy = dirs[1], dz = dirs[2];
    const float u_i  = (float)lane / 63.0f;
    const float u_n  = (float)(lane + 1) / 63.0f;
    const float tv    = nearv * (1.f - u_i) + farv * u_i;
    const float tnext = nearv * (1.f - u_n) + farv * u_n;

    const float4 rr = *(const float4*)(&sR[lane*4]);
    const float dens = fmaxf(rr.w, 0.f);

    const float dnorm = sqrtf(dx*dx + dy*dy + dz*dz);
    const float tdist = (lane == NC-1) ? 1e10f : (tnext - tv);
    const float dd    = fminf(dens * (tdist * dnorm), 1e4f);
    const float incl  = wave_incl_scan(dd, lane);
    const float excl  = incl - dd;
    const float alpha = 1.f - expf(-dd);     // pdf-critical: accurate
    const float trans = expf(-excl);         // pdf-critical: accurate
    const float w     = alpha * trans;

    const float wnext = __shfl_down(w, 1);
    const float pw = (lane < NC-2) ? wnext : 0.f;
    const float ws_sum = wave_sum(pw);
    const float pad = fmaxf(1e-5f - ws_sum, 0.f);
    const float wsp = ws_sum + pad;
    const float pdf = (lane < NC-2) ? (pw + pad * (1.f/62.f)) / wsp : 0.f;
    float ip  = wave_incl_scan(pdf, lane);
    ip = wave_incl_max_scan(ip, lane);       // exact monotone
    if (lane < 61)  sCdf[lane+1] = fminf(ip, 1.f);
    if (lane == 61) sCdf[0]  = 0.f;
    if (lane == 62) sCdf[62] = 1.f;
    __builtin_amdgcn_wave_barrier();

    const float ustep = (1.0f - 1.1920929e-07f) / 127.0f;
#pragma unroll
    for (int r = 0; r < 2; ++r) {
      const int k = lane + 64*r;
      const float u = k * ustep;
      int lo = 0, hi = 61;
      while (lo < hi) {
        const int mid = (lo + hi + 1) >> 1;
        if (sCdf[mid] <= u) lo = mid; else hi = mid - 1;
      }
      const int J = lo;
      const float cg0 = sCdf[J],  cg1 = sCdf[J+1];
      const float bg0 = sBins[J], bg1 = sBins[J+1];
      const float denom = cg1 - cg0;
      const float num   = u - cg0;
      float tt;
      if (denom > 0.f) tt = fminf(fmaxf(num / denom, 0.f), 1.f);
      else             tt = (num > 0.f) ? 1.f : 0.f;
      sZs[k] = fmaf(tt, bg1 - bg0, bg0);
    }
    __builtin_amdgcn_wave_barrier();

    {
      int l = 0, r = NF;
      while (l < r) { const int m = (l + r) >> 1; if (sZs[m] < tv) l = m + 1; else r = m; }
      sZv0[lane + l] = tv;
    }
#pragma unroll
    for (int r2 = 0; r2 < 2; ++r2) {
      const int k = lane + 64*r2;
      const float z = sZs[k];
      int l = 0, r = NC;
      while (l < r) { const int m = (l + r) >> 1; if (sT[m] <= z) l = m + 1; else r = m; }
      sZv0[k + l] = z;
    }
    __builtin_amdgcn_wave_barrier();

#pragma unroll
    for (int s = 0; s < 3; ++s) gz0[lane + 64*s] = sZv0[lane + 64*s];
  }
}

// -------- Kernel 2: 4 waves = 4 rays per block; SINGLE fine R buffer --------
__global__ __launch_bounds__(256) void nerf_fused_kernel(
    const float* __restrict__ origins, const float* __restrict__ dirs,
    const float* __restrict__ nearp, const float* __restrict__ farp,
    const float* __restrict__ bkgd,
    const float* __restrict__ w1c, const float* __restrict__ b1c,
    const float* __restrict__ w2c, const float* __restrict__ b2c,
    const float* __restrict__ wrc, const float* __restrict__ brc,
    const float* __restrict__ wdc, const float* __restrict__ bdc,
    const float* __restrict__ w1f, const float* __restrict__ b1f,
    const float* __restrict__ w2f, const float* __restrict__ b2f_,
    const float* __restrict__ wrf, const float* __restrict__ brf,
    const float* __restrict__ wdf, const float* __restrict__ bdf,
    const float* __restrict__ gz0, float* __restrict__ out)
{
  __shared__ WLds sWc, sWf;
  __shared__ float sHWc[H][4], sHWf[H][4];
  __shared__ float sB2c[H], sB2f[H];
  __shared__ float sT[4][NC];
  __shared__ float sBins[4][NC];
  __shared__ float sCdf[4][NC];
  __shared__ float sZs[4][NF];
  __shared__ float sZv[4][NZ];
  __shared__ float sZv0[NZ];                // ray 0's fine z row (quirk)
  __shared__ float sR[4][256];              // per-wave logits, SINGLE buffer
  __shared__ __align__(16) float2 sAB[4][H];// per-wave {a,b} for layer 1

  const int tid  = threadIdx.x;
  const int wv   = tid >> 6;
  const int lane = tid & 63;
  const int ray  = blockIdx.x * 4 + wv;

  if (tid < 64) {
    const int k = tid;
    sWc.W1b[k][0] = w1c[0*H + k];
    sWc.W1b[k][1] = w1c[1*H + k];
    sWc.W1b[k][2] = w1c[2*H + k];
    sWc.W1b[k][3] = b1c[k];
    sHWc[k][0] = wrc[k*3+0]; sHWc[k][1] = wrc[k*3+1];
    sHWc[k][2] = wrc[k*3+2]; sHWc[k][3] = wdc[k];
    sB2c[k] = b2c[k];
  } else if (tid < 128) {
    const int k = tid - 64;
    sWf.W1b[k][0] = w1f[0*H + k];
    sWf.W1b[k][1] = w1f[1*H + k];
    sWf.W1b[k][2] = w1f[2*H + k];
    sWf.W1b[k][3] = b1f[k];
    sHWf[k][0] = wrf[k*3+0]; sHWf[k][1] = wrf[k*3+1];
    sHWf[k][2] = wrf[k*3+2]; sHWf[k][3] = wdf[k];
    sB2f[k] = b2f_[k];
  }
  if (tid < NZ) sZv0[tid] = gz0[tid];       // z0 row from kernel 1
  __syncthreads();

  float* R = sR[wv];
  float2* ABw = &sAB[wv][0];

  // ---- coarse pass (own ray only) ----
  {
    MfmaW Mc;
    load_mfma_weights(lane, w2c, brc, bdc, Mc);
    coarse_pass(ray, lane, origins, dirs, nearp, farp, bkgd,
                sWc, Mc, sHWc, sB2c, R, ABw,
                sT[wv], sBins[wv], sCdf[wv], sZs[wv], sZv[wv], true, out);
  }

  // ---- fine pass: 3 batches of 64 samples, rendering fused per-batch ----
  MfmaW Mf;
  load_mfma_weights(lane, w2f, brf, bdf, Mf);

  const float ox = origins[ray*3+0], oy = origins[ray*3+1], oz = origins[ray*3+2];
  const float dx = dirs[ray*3+0],    dy = dirs[ray*3+1],    dz = dirs[ray*3+2];
  const float dnorm = sqrtf(dx*dx + dy*dy + dz*dz);

  {
    const float4 wvv = *(const float4*)(&sWf.W1b[lane][0]);
    const float a = fmaf(ox, wvv.x, fmaf(oy, wvv.y, fmaf(oz, wvv.z, wvv.w)));
    const float b = fmaf(dx, wvv.x, fmaf(dy, wvv.y, dz * wvv.z));
    ABw[lane] = (float2){a, b};
  }
  __builtin_amdgcn_wave_barrier();

  float aw = 0.f, awz = 0.f, ac0 = 0.f, ac1 = 0.f, ac2 = 0.f, awz0 = 0.f;
  float offset = 0.f;
#pragma unroll 1
  for (int s = 0; s < 3; ++s) {
    mlp_mfma_batch(lane, ABw, &sZv[wv][64*s], Mf, sHWf, sB2f, R);
    const int i = lane + 64*s;
    const float4 rr = *(const float4*)(&R[lane*4]);
    const float dens = fmaxf(rr.w, 0.f);
    const float zcv = sZv[wv][i];
    const float znv = (i < NZ-1) ? sZv[wv][i+1] : 0.f;
    const float td  = (i == NZ-1) ? 1e10f : fmaxf(znv - zcv, 0.f);
    const float ddv = fminf(dens * (td * dnorm), 1e4f);
    const float incl  = wave_incl_scan(ddv, lane);
    const float exclv = offset + incl - ddv;
    offset += __shfl(incl, 63);
    const float wgt = (1.f - __expf(-ddv)) * __expf(-exclv);  // output-only: fast
    aw   += wgt;
    awz  += wgt * zcv;
    ac0  += wgt * fsig(rr.x);
    ac1  += wgt * fsig(rr.y);
    ac2  += wgt * fsig(rr.z);
    awz0 += wgt * sZv0[i];
    __builtin_amdgcn_wave_barrier();   // reads of R done before next overwrite
  }
  aw  = wave_sum(aw);  awz = wave_sum(awz); ac0 = wave_sum(ac0);
  ac1 = wave_sum(ac1); ac2 = wave_sum(ac2); awz0 = wave_sum(awz0);

  if (lane == 0) {
    const float bk0 = bkgd[0], bk1 = bkgd[1], bk2 = bkgd[2];
    const float o0x = origins[0], o0y = origins[1], o0z = origins[2];
    const float d0x = dirs[0],    d0y = dirs[1],    d0z = dirs[2];
    const float oma = 1.f - aw;
    float* o = out + (size_t)ray * 16 + 8;
    o[0] = ac0 + bk0 * oma;
    o[1] = ac1 + bk1 * oma;
    o[2] = ac2 + bk2 * oma;
    o[3] = awz;
    o[4] = aw;
    o[5] = aw * o0x + awz0 * d0x;
    o[6] = aw * o0y + awz0 * d0y;
    o[7] = aw * o0z + awz0 * d0z;
  }
}

extern "C" void kernel_launch(void* const* d_in, const int* in_sizes, int n_in,
                              void* d_out, int out_size, void* d_ws, size_t ws_size,
                              hipStream_t stream) {
  const float* origins = (const float*)d_in[0];
  const float* dirs    = (const float*)d_in[1];
  const float* nearp   = (const float*)d_in[2];
  const float* farp    = (const float*)d_in[3];
  const float* bkgd    = (const float*)d_in[4];
  const float* w1c  = (const float*)d_in[5];
  const float* b1c  = (const float*)d_in[6];
  const float* w2c  = (const float*)d_in[7];
  const float* b2c  = (const float*)d_in[8];
  const float* wrc  = (const float*)d_in[9];
  const float* brc  = (const float*)d_in[10];
  const float* wdc  = (const float*)d_in[11];
  const float* bdc  = (const float*)d_in[12];
  const float* w1f  = (const float*)d_in[13];
  const float* b1f  = (const float*)d_in[14];
  const float* w2f  = (const float*)d_in[15];
  const float* b2f_ = (const float*)d_in[16];
  const float* wrf  = (const float*)d_in[17];
  const float* brf  = (const float*)d_in[18];
  const float* wdf  = (const float*)d_in[19];
  const float* bdf  = (const float*)d_in[20];

  float* gz0 = (float*)d_ws;   // 192 floats = 768 B of scratch (proven size)

  nerf_z0_kernel<<<1, 256, 0, stream>>>(
      origins, dirs, nearp, farp,
      w1c, b1c, w2c, b2c, wrc, brc, wdc, bdc, gz0);

  nerf_fused_kernel<<<NRAYS/4, 256, 0, stream>>>(
      origins, dirs, nearp, farp, bkgd,
      w1c, b1c, w2c, b2c, wrc, brc, wdc, bdc,
      w1f, b1f, w2f, b2f_, wrf, brf, wdf, bdf,
      gz0, (float*)d_out);
}

// Round 9
// 297.392 us; speedup vs baseline: 1.3997x; 1.3997x over previous
//
#include <hip/hip_runtime.h>
#include <math.h>

#define NRAYS 16384
#define NC    64
#define NF    128
#define NZ    192   // NC + NF
#define H     64

typedef __attribute__((ext_vector_type(8))) short bf16x8;  // 8 bf16 (4 VGPRs)
typedef __attribute__((ext_vector_type(4))) float f32x4;   // MFMA C/D
typedef __attribute__((ext_vector_type(4))) int   i32x4;

// R18/R20 lesson (twice-confirmed): ANY f32x2 packed-math use costs +8 VGPR
// (even-pair alignment fragments allocation) -> occupancy halves at the 128
// cliff -> net loss. No f32x2 anywhere in this kernel.

// One-instruction pack: result = (a & 0xFFFF0000) | (b >> 16).
// v_perm_b32 byte-select: sel bytes 0-3 pick from src1(b), 4-7 from src0(a);
// result bytes {3,2,1,0} = {a3,a2,b3,b2}. Bit-identical to the 3-op form
// (verified on-HW in R20, absmax unchanged). Zero register pressure.
__device__ __forceinline__ int pack_hi16(unsigned a, unsigned b) {
  return (int)__builtin_amdgcn_perm(a, b, 0x07060302u);
}

__device__ __forceinline__ float wave_incl_scan(float v, int lane) {
#pragma unroll
  for (int off = 1; off < 64; off <<= 1) {
    float n = __shfl_up(v, off);
    v = (lane >= off) ? v + n : v;
  }
  return v;
}

__device__ __forceinline__ float wave_incl_max_scan(float v, int lane) {
#pragma unroll
  for (int off = 1; off < 64; off <<= 1) {
    float n = __shfl_up(v, off);
    v = (lane >= off) ? fmaxf(v, n) : v;
  }
  return v;
}

__device__ __forceinline__ float wave_sum(float v) {
#pragma unroll
  for (int off = 32; off > 0; off >>= 1) v += __shfl_xor(v, off);
  return v;
}

// fp32 -> bf16 hi + bf16 lo (truncation split; 3-term MFMA has rel err ~2^-15).
__device__ __forceinline__ void split_bf16(float f, short& hi, short& lo) {
  unsigned u = __float_as_uint(f);
  hi = (short)(u >> 16);
  float rem = f - __uint_as_float(u & 0xFFFF0000u);   // exact
  lo = (short)(__float_as_uint(rem) >> 16);
}

// Fast sigmoid: OUTPUT-ONLY paths (never feeds the coarse pdf->cdf->sampling
// chain, which must stay bit-stable: bin flips cost O(0.03) absmax).
__device__ __forceinline__ float fsig(float x) {
  return __builtin_amdgcn_rcpf(1.f + __expf(-x));
}

// Layer-1 weights in LDS — read per-batch via a/b precompute.
struct __align__(16) WLds {
  float W1b[H][4];   // {w1[0][k], w1[1][k], w1[2][k], b1[k]}
};

// Register-resident w2 fragments (hi/lo split) + head bias.
struct MfmaW {
  bf16x8 Bhi[2][4], Blo[2][4];  // w2 [kt][jt]
  float  hbown;                 // head bias for this lane's c = n16&3
};

__device__ __forceinline__ void load_mfma_weights(
    int lane,
    const float* __restrict__ w2,
    const float* __restrict__ br, const float* __restrict__ bd,
    MfmaW& M)
{
  const int quad = lane >> 4, n16 = lane & 15;
#pragma unroll
  for (int kt = 0; kt < 2; ++kt) {
#pragma unroll
    for (int jt = 0; jt < 4; ++jt) {
#pragma unroll
      for (int j = 0; j < 8; ++j) {
        const int k = kt*32 + quad*8 + j;
        short hi, lo;
        split_bf16(w2[k*H + jt*16 + n16], hi, lo);
        M.Bhi[kt][jt][j] = hi; M.Blo[kt][jt][j] = lo;
      }
    }
  }
  const int c = n16 & 3;
  M.hbown = (c == 0) ? br[0] : (c == 1) ? br[1] : (c == 2) ? br[2] : bd[0];
}

// ONE mt sub-batch (16 samples) — used by kernel 1's 4-wave MLP (mt = wave id).
// Identical per-sample arithmetic to the monolithic batch below.
__device__ __forceinline__ void mlp_mfma_batch_one(
    int mt, int lane, const float2* __restrict__ AB,
    const float* __restrict__ zsrc, const MfmaW& M,
    const float (*__restrict__ sHW)[4], const float* __restrict__ sB2,
    float* __restrict__ R)
{
  const int quad = lane >> 4, n16 = lane & 15;
  const float z = zsrc[mt*16 + n16];
  f32x4 C[4];
#pragma unroll
  for (int jt = 0; jt < 4; ++jt) {
    const float b2v = sB2[jt*16 + n16];
    C[jt] = (f32x4){b2v, b2v, b2v, b2v};
  }
#pragma unroll
  for (int kt = 0; kt < 2; ++kt) {
    const float4* abp = (const float4*)(AB + kt*32 + quad*8);
    i32x4 hip, lop;
#pragma unroll
    for (int j2 = 0; j2 < 4; ++j2) {
      const float4 p = abp[j2];                 // {a0,b0,a1,b1}
      const float h0 = fmaxf(fmaf(z, p.y, p.x), 0.f);
      const float h1 = fmaxf(fmaf(z, p.w, p.z), 0.f);
      const unsigned u0 = __float_as_uint(h0), u1 = __float_as_uint(h1);
      hip[j2] = pack_hi16(u1, u0);
      const float r0 = h0 - __uint_as_float(u0 & 0xFFFF0000u);
      const float r1 = h1 - __uint_as_float(u1 & 0xFFFF0000u);
      lop[j2] = pack_hi16(__float_as_uint(r1), __float_as_uint(r0));
    }
    union { i32x4 i; bf16x8 h; } uh, ul;
    uh.i = hip; ul.i = lop;
#pragma unroll
    for (int jt = 0; jt < 4; ++jt) {
      C[jt] = __builtin_amdgcn_mfma_f32_16x16x32_bf16(uh.h, M.Bhi[kt][jt], C[jt], 0, 0, 0);
      C[jt] = __builtin_amdgcn_mfma_f32_16x16x32_bf16(ul.h, M.Bhi[kt][jt], C[jt], 0, 0, 0);
      C[jt] = __builtin_amdgcn_mfma_f32_16x16x32_bf16(uh.h, M.Blo[kt][jt], C[jt], 0, 0, 0);
    }
  }
  float P[16];
#pragma unroll
  for (int i = 0; i < 16; ++i) P[i] = 0.f;
#pragma unroll
  for (int jt = 0; jt < 4; ++jt) {
    const float4 hwv = *(const float4*)(&sHW[jt*16 + n16][0]);
#pragma unroll
    for (int r = 0; r < 4; ++r) {
      const float h2v = fmaxf(C[jt][r], 0.f);
      P[r*4 + 0] = fmaf(h2v, hwv.x, P[r*4 + 0]);
      P[r*4 + 1] = fmaf(h2v, hwv.y, P[r*4 + 1]);
      P[r*4 + 2] = fmaf(h2v, hwv.z, P[r*4 + 2]);
      P[r*4 + 3] = fmaf(h2v, hwv.w, P[r*4 + 3]);
    }
  }
  const bool b0 = (n16 & 1), b1 = (n16 & 2), b2_ = (n16 & 4), b3 = (n16 & 8);
  float Q[8];
#pragma unroll
  for (int s = 0; s < 8; ++s) {
    const float give = b0 ? P[2*s] : P[2*s+1];
    const float keep = b0 ? P[2*s+1] : P[2*s];
    Q[s] = keep + __shfl_xor(give, 1);
  }
  float U[4];
#pragma unroll
  for (int t = 0; t < 4; ++t) {
    const float give = b1 ? Q[2*t] : Q[2*t+1];
    const float keep = b1 ? Q[2*t+1] : Q[2*t];
    U[t] = keep + __shfl_xor(give, 2);
  }
  float V[2];
#pragma unroll
  for (int u = 0; u < 2; ++u) {
    const float give = b2_ ? U[2*u] : U[2*u+1];
    const float keep = b2_ ? U[2*u+1] : U[2*u];
    V[u] = keep + __shfl_xor(give, 4);
  }
  {
    const float give = b3 ? V[0] : V[1];
    const float keep = b3 ? V[1] : V[0];
    const float total = keep + __shfl_xor(give, 8);
    R[mt*64 + lane] = total + M.hbown;   // coalesced: addr = sample*4 + c
  }
}

// One 64-sample MLP batch (monolithic, R19 structure) — used by kernel 2.
__device__ __forceinline__ void mlp_mfma_batch(
    int lane, const float2* __restrict__ AB,
    const float* __restrict__ zsrc, const MfmaW& M,
    const float (*__restrict__ sHW)[4], const float* __restrict__ sB2,
    float* __restrict__ R)
{
  const int quad = lane >> 4, n16 = lane & 15;
  float b2q[4];
#pragma unroll
  for (int jt = 0; jt < 4; ++jt) b2q[jt] = sB2[jt*16 + n16];
#pragma unroll 1   // rolled: prevents register blow-up (R5/R6 lesson)
  for (int mt = 0; mt < 4; ++mt) {
    const float z = zsrc[mt*16 + n16];
    f32x4 C[4];
#pragma unroll
    for (int jt = 0; jt < 4; ++jt)
      C[jt] = (f32x4){b2q[jt], b2q[jt], b2q[jt], b2q[jt]};
#pragma unroll
    for (int kt = 0; kt < 2; ++kt) {
      const float4* abp = (const float4*)(AB + kt*32 + quad*8);
      i32x4 hip, lop;
#pragma unroll
      for (int j2 = 0; j2 < 4; ++j2) {
        const float4 p = abp[j2];                 // {a0,b0,a1,b1}
        const float h0 = fmaxf(fmaf(z, p.y, p.x), 0.f);
        const float h1 = fmaxf(fmaf(z, p.w, p.z), 0.f);
        const unsigned u0 = __float_as_uint(h0), u1 = __float_as_uint(h1);
        hip[j2] = pack_hi16(u1, u0);
        const float r0 = h0 - __uint_as_float(u0 & 0xFFFF0000u);
        const float r1 = h1 - __uint_as_float(u1 & 0xFFFF0000u);
        lop[j2] = pack_hi16(__float_as_uint(r1), __float_as_uint(r0));
      }
      union { i32x4 i; bf16x8 h; } uh, ul;
      uh.i = hip; ul.i = lop;
#pragma unroll
      for (int jt = 0; jt < 4; ++jt) {
        C[jt] = __builtin_amdgcn_mfma_f32_16x16x32_bf16(uh.h, M.Bhi[kt][jt], C[jt], 0, 0, 0);
        C[jt] = __builtin_amdgcn_mfma_f32_16x16x32_bf16(ul.h, M.Bhi[kt][jt], C[jt], 0, 0, 0);
        C[jt] = __builtin_amdgcn_mfma_f32_16x16x32_bf16(uh.h, M.Blo[kt][jt], C[jt], 0, 0, 0);
      }
    }
    float P[16];
#pragma unroll
    for (int i = 0; i < 16; ++i) P[i] = 0.f;
#pragma unroll
    for (int jt = 0; jt < 4; ++jt) {
      const float4 hwv = *(const float4*)(&sHW[jt*16 + n16][0]);
#pragma unroll
      for (int r = 0; r < 4; ++r) {
        const float h2v = fmaxf(C[jt][r], 0.f);
        P[r*4 + 0] = fmaf(h2v, hwv.x, P[r*4 + 0]);
        P[r*4 + 1] = fmaf(h2v, hwv.y, P[r*4 + 1]);
        P[r*4 + 2] = fmaf(h2v, hwv.z, P[r*4 + 2]);
        P[r*4 + 3] = fmaf(h2v, hwv.w, P[r*4 + 3]);
      }
    }
    const bool b0 = (n16 & 1), b1 = (n16 & 2), b2_ = (n16 & 4), b3 = (n16 & 8);
    float Q[8];
#pragma unroll
    for (int s = 0; s < 8; ++s) {
      const float give = b0 ? P[2*s] : P[2*s+1];
      const float keep = b0 ? P[2*s+1] : P[2*s];
      Q[s] = keep + __shfl_xor(give, 1);
    }
    float U[4];
#pragma unroll
    for (int t = 0; t < 4; ++t) {
      const float give = b1 ? Q[2*t] : Q[2*t+1];
      const float keep = b1 ? Q[2*t+1] : Q[2*t];
      U[t] = keep + __shfl_xor(give, 2);
    }
    float V[2];
#pragma unroll
    for (int u = 0; u < 2; ++u) {
      const float give = b2_ ? U[2*u] : U[2*u+1];
      const float keep = b2_ ? U[2*u+1] : U[2*u];
      V[u] = keep + __shfl_xor(give, 4);
    }
    {
      const float give = b3 ? V[0] : V[1];
      const float keep = b3 ? V[1] : V[0];
      const float total = keep + __shfl_xor(give, 8);
      R[mt*64 + lane] = total + M.hbown;   // coalesced: addr = sample*4 + c
    }
  }
  __builtin_amdgcn_wave_barrier();     // R complete before readback
}

// Coarse pass for one ray, ONE wave, wave-private LDS scratch.
// NOTE: alpha/trans keep ACCURATE expf — they feed the pdf->cdf->inverse-CDF
// chain; perturbing them can flip binary-search bins (absmax blowup).
__device__ __forceinline__ void coarse_pass(
    int ray, int lane,
    const float* __restrict__ origins, const float* __restrict__ dirs,
    const float* __restrict__ nearp, const float* __restrict__ farp,
    const float* __restrict__ bkgd,
    const WLds& W, const MfmaW& M,
    const float (*__restrict__ sHW)[4], const float* __restrict__ sB2,
    float* __restrict__ R, float2* __restrict__ sAB,
    float* __restrict__ sT, float* __restrict__ sBins,
    float* __restrict__ sCdf, float* __restrict__ sZs,
    float* __restrict__ zdst, bool emit, float* __restrict__ out)
{
  const float nearv = nearp[ray];
  const float farv  = farp[ray];
  const float ox = origins[ray*3+0], oy = origins[ray*3+1], oz = origins[ray*3+2];
  const float dx = dirs[ray*3+0],    dy = dirs[ray*3+1],    dz = dirs[ray*3+2];

  {
    const float4 wv = *(const float4*)(&W.W1b[lane][0]);
    const float a = fmaf(ox, wv.x, fmaf(oy, wv.y, fmaf(oz, wv.z, wv.w)));
    const float b = fmaf(dx, wv.x, fmaf(dy, wv.y, dz * wv.z));
    sAB[lane] = (float2){a, b};
  }

  const float u_i  = (float)lane / 63.0f;
  const float u_n  = (float)(lane + 1) / 63.0f;
  const float tv    = nearv * (1.f - u_i) + farv * u_i;
  const float tnext = nearv * (1.f - u_n) + farv * u_n;

  sT[lane] = tv;
  if (lane < NC-1) sBins[lane] = 0.5f * (tv + tnext);
  zdst[lane] = 0.f; zdst[lane+64] = 0.f; zdst[lane+128] = 0.f;
  __builtin_amdgcn_wave_barrier();     // sT + sAB ready for the batch

  mlp_mfma_batch(lane, sAB, sT, M, sHW, sB2, R);
  const float4 rr = *(const float4*)(&R[lane*4]);
  const float rgb0 = fsig(rr.x), rgb1 = fsig(rr.y), rgb2 = fsig(rr.z);
  const float dens = fmaxf(rr.w, 0.f);

  const float dnorm = sqrtf(dx*dx + dy*dy + dz*dz);
  const float tdist = (lane == NC-1) ? 1e10f : (tnext - tv);
  const float dd    = fminf(dens * (tdist * dnorm), 1e4f);
  const float incl  = wave_incl_scan(dd, lane);
  const float excl  = incl - dd;
  const float alpha = 1.f - expf(-dd);     // pdf-critical: accurate
  const float trans = expf(-excl);         // pdf-critical: accurate
  const float w     = alpha * trans;

  if (emit) {
    const float near0 = nearp[0], far0 = farp[0];
    const float t0v   = near0 * (1.f - u_i) + far0 * u_i;
    const float s_w   = wave_sum(w);
    const float s_wt  = wave_sum(w * tv);
    const float s_c0  = wave_sum(w * rgb0);
    const float s_c1  = wave_sum(w * rgb1);
    const float s_c2  = wave_sum(w * rgb2);
    const float s_wt0 = wave_sum(w * t0v);
    if (lane == 0) {
      const float bk0 = bkgd[0], bk1 = bkgd[1], bk2 = bkgd[2];
      const float o0x = origins[0], o0y = origins[1], o0z = origins[2];
      const float d0x = dirs[0],    d0y = dirs[1],    d0z = dirs[2];
      const float oma = 1.f - s_w;
      float* o = out + (size_t)ray * 16;
      o[0] = s_c0 + bk0 * oma;
      o[1] = s_c1 + bk1 * oma;
      o[2] = s_c2 + bk2 * oma;
      o[3] = s_wt;
      o[4] = s_w;
      o[5] = s_w * o0x + s_wt0 * d0x;
      o[6] = s_w * o0y + s_wt0 * d0y;
      o[7] = s_w * o0z + s_wt0 * d0z;
    }
  }

  // ---- PDF -> CDF (62 weights = w[1..62]) ----
  const float wnext = __shfl_down(w, 1);
  const float pw = (lane < NC-2) ? wnext : 0.f;
  const float ws_sum = wave_sum(pw);
  const float pad = fmaxf(1e-5f - ws_sum, 0.f);
  const float wsp = ws_sum + pad;
  const float pdf = (lane < NC-2) ? (pw + pad * (1.f/62.f)) / wsp : 0.f;
  float ip  = wave_incl_scan(pdf, lane);
  ip = wave_incl_max_scan(ip, lane);       // exact monotone
  if (lane < 61)  sCdf[lane+1] = fminf(ip, 1.f);
  if (lane == 61) sCdf[0]  = 0.f;
  if (lane == 62) sCdf[62] = 1.f;
  __builtin_amdgcn_wave_barrier();

  // ---- inverse-CDF: 128 samples, 2 per lane ----
  const float ustep = (1.0f - 1.1920929e-07f) / 127.0f;
#pragma unroll
  for (int r = 0; r < 2; ++r) {
    const int k = lane + 64*r;
    const float u = k * ustep;
    int lo = 0, hi = 61;
    while (lo < hi) {
      const int mid = (lo + hi + 1) >> 1;
      if (sCdf[mid] <= u) lo = mid; else hi = mid - 1;
    }
    const int J = lo;
    const float cg0 = sCdf[J],  cg1 = sCdf[J+1];
    const float bg0 = sBins[J], bg1 = sBins[J+1];
    const float denom = cg1 - cg0;
    const float num   = u - cg0;
    float tt;
    if (denom > 0.f) tt = fminf(fmaxf(num / denom, 0.f), 1.f);
    else             tt = (num > 0.f) ? 1.f : 0.f;
    sZs[k] = fmaf(tt, bg1 - bg0, bg0);
  }
  __builtin_amdgcn_wave_barrier();

  // ---- stable rank merge of sorted t (64) and z (128) into zdst (192) ----
  {
    int l = 0, r = NF;
    while (l < r) { const int m = (l + r) >> 1; if (sZs[m] < tv) l = m + 1; else r = m; }
    zdst[lane + l] = tv;
  }
#pragma unroll
  for (int r2 = 0; r2 < 2; ++r2) {
    const int k = lane + 64*r2;
    const float z = sZs[k];
    int l = 0, r = NC;
    while (l < r) { const int m = (l + r) >> 1; if (sT[m] <= z) l = m + 1; else r = m; }
    zdst[k + l] = z;
  }
  __builtin_amdgcn_wave_barrier();
}

// -------- Kernel 1: ONE block, 4 waves (R17 structure, verified). MLP is
// 4-wave (wave wv computes mt = wv); the serial tail runs on wave 0. --------
__global__ __launch_bounds__(256) void nerf_z0_kernel(
    const float* __restrict__ origins, const float* __restrict__ dirs,
    const float* __restrict__ nearp, const float* __restrict__ farp,
    const float* __restrict__ w1c, const float* __restrict__ b1c,
    const float* __restrict__ w2c, const float* __restrict__ b2c,
    const float* __restrict__ wrc, const float* __restrict__ brc,
    const float* __restrict__ wdc, const float* __restrict__ bdc,
    float* __restrict__ gz0)
{
  __shared__ WLds sW;
  __shared__ float sHW[H][4];
  __shared__ float sB2[H];
  __shared__ float sT[NC], sBins[NC], sCdf[NC], sZs[NF], sZv0[NZ];
  __shared__ float sR[256];
  __shared__ __align__(16) float2 sAB[H];

  const int tid  = threadIdx.x;
  const int wv   = tid >> 6;
  const int lane = tid & 63;

  if (tid < 64) {
    const int k = tid;
    sW.W1b[k][0] = w1c[0*H + k];
    sW.W1b[k][1] = w1c[1*H + k];
    sW.W1b[k][2] = w1c[2*H + k];
    sW.W1b[k][3] = b1c[k];
    sHW[k][0] = wrc[k*3 + 0];
    sHW[k][1] = wrc[k*3 + 1];
    sHW[k][2] = wrc[k*3 + 2];
    sHW[k][3] = wdc[k];
    sB2[k]    = b2c[k];
  }

  MfmaW Mc;                         // every wave needs the fragments
  load_mfma_weights(lane, w2c, brc, bdc, Mc);
  __syncthreads();                  // #1: tables visible to all waves

  const float nearv = nearp[0];
  const float farv  = farp[0];

  // ---- geometry (wave 0; identical formulas to coarse_pass) ----
  if (wv == 0) {
    const float ox = origins[0], oy = origins[1], oz = origins[2];
    const float dx = dirs[0],    dy = dirs[1],    dz = dirs[2];
    const float4 wvv = *(const float4*)(&sW.W1b[lane][0]);
    const float a = fmaf(ox, wvv.x, fmaf(oy, wvv.y, fmaf(oz, wvv.z, wvv.w)));
    const float b = fmaf(dx, wvv.x, fmaf(dy, wvv.y, dz * wvv.z));
    sAB[lane] = (float2){a, b};

    const float u_i  = (float)lane / 63.0f;
    const float u_n  = (float)(lane + 1) / 63.0f;
    const float tv    = nearv * (1.f - u_i) + farv * u_i;
    const float tnext = nearv * (1.f - u_n) + farv * u_n;
    sT[lane] = tv;
    if (lane < NC-1) sBins[lane] = 0.5f * (tv + tnext);
    sZv0[lane] = 0.f; sZv0[lane+64] = 0.f; sZv0[lane+128] = 0.f;
  }
  __syncthreads();                  // #2: sAB/sT ready for all waves

  // ---- 4-wave MLP, wave wv does mt = wv ----
  mlp_mfma_batch_one(wv, lane, sAB, sT, Mc, sHW, sB2, sR);
  __syncthreads();                  // #3: sR complete

  // ---- serial tail: wave 0 only (verified R15 tail, emit=false) ----
  if (wv == 0) {
    const float dx = dirs[0], dy = dirs[1], dz = dirs[2];
    const float u_i  = (float)lane / 63.0f;
    const float u_n  = (float)(lane + 1) / 63.0f;
    const float tv    = nearv * (1.f - u_i) + farv * u_i;
    const float tnext = nearv * (1.f - u_n) + farv * u_n;

    const float4 rr = *(const float4*)(&sR[lane*4]);
    const float dens = fmaxf(rr.w, 0.f);

    const float dnorm = sqrtf(dx*dx + dy*dy + dz*dz);
    const float tdist = (lane == NC-1) ? 1e10f : (tnext - tv);
    const float dd    = fminf(dens * (tdist * dnorm), 1e4f);
    const float incl  = wave_incl_scan(dd, lane);
    const float excl  = incl - dd;
    const float alpha = 1.f - expf(-dd);     // pdf-critical: accurate
    const float trans = expf(-excl);         // pdf-critical: accurate
    const float w     = alpha * trans;

    const float wnext = __shfl_down(w, 1);
    const float pw = (lane < NC-2) ? wnext : 0.f;
    const float ws_sum = wave_sum(pw);
    const float pad = fmaxf(1e-5f - ws_sum, 0.f);
    const float wsp = ws_sum + pad;
    const float pdf = (lane < NC-2) ? (pw + pad * (1.f/62.f)) / wsp : 0.f;
    float ip  = wave_incl_scan(pdf, lane);
    ip = wave_incl_max_scan(ip, lane);       // exact monotone
    if (lane < 61)  sCdf[lane+1] = fminf(ip, 1.f);
    if (lane == 61) sCdf[0]  = 0.f;
    if (lane == 62) sCdf[62] = 1.f;
    __builtin_amdgcn_wave_barrier();

    const float ustep = (1.0f - 1.1920929e-07f) / 127.0f;
#pragma unroll
    for (int r = 0; r < 2; ++r) {
      const int k = lane + 64*r;
      const float u = k * ustep;
      int lo = 0, hi = 61;
      while (lo < hi) {
        const int mid = (lo + hi + 1) >> 1;
        if (sCdf[mid] <= u) lo = mid; else hi = mid - 1;
      }
      const int J = lo;
      const float cg0 = sCdf[J],  cg1 = sCdf[J+1];
      const float bg0 = sBins[J], bg1 = sBins[J+1];
      const float denom = cg1 - cg0;
      const float num   = u - cg0;
      float tt;
      if (denom > 0.f) tt = fminf(fmaxf(num / denom, 0.f), 1.f);
      else             tt = (num > 0.f) ? 1.f : 0.f;
      sZs[k] = fmaf(tt, bg1 - bg0, bg0);
    }
    __builtin_amdgcn_wave_barrier();

    {
      int l = 0, r = NF;
      while (l < r) { const int m = (l + r) >> 1; if (sZs[m] < tv) l = m + 1; else r = m; }
      sZv0[lane + l] = tv;
    }
#pragma unroll
    for (int r2 = 0; r2 < 2; ++r2) {
      const int k = lane + 64*r2;
      const float z = sZs[k];
      int l = 0, r = NC;
      while (l < r) { const int m = (l + r) >> 1; if (sT[m] <= z) l = m + 1; else r = m; }
      sZv0[k + l] = z;
    }
    __builtin_amdgcn_wave_barrier();

#pragma unroll
    for (int s = 0; s < 3; ++s) gz0[lane + 64*s] = sZv0[lane + 64*s];
  }
}

// -------- Kernel 2: 4 waves = 4 rays per block; SINGLE fine R buffer --------
__global__ __launch_bounds__(256) void nerf_fused_kernel(
    const float* __restrict__ origins, const float* __restrict__ dirs,
    const float* __restrict__ nearp, const float* __restrict__ farp,
    const float* __restrict__ bkgd,
    const float* __restrict__ w1c, const float* __restrict__ b1c,
    const float* __restrict__ w2c, const float* __restrict__ b2c,
    const float* __restrict__ wrc, const float* __restrict__ brc,
    const float* __restrict__ wdc, const float* __restrict__ bdc,
    const float* __restrict__ w1f, const float* __restrict__ b1f,
    const float* __restrict__ w2f, const float* __restrict__ b2f_,
    const float* __restrict__ wrf, const float* __restrict__ brf,
    const float* __restrict__ wdf, const float* __restrict__ bdf,
    const float* __restrict__ gz0, float* __restrict__ out)
{
  __shared__ WLds sWc, sWf;
  __shared__ float sHWc[H][4], sHWf[H][4];
  __shared__ float sB2c[H], sB2f[H];
  __shared__ float sT[4][NC];
  __shared__ float sBins[4][NC];
  __shared__ float sCdf[4][NC];
  __shared__ float sZs[4][NF];
  __shared__ float sZv[4][NZ];
  __shared__ float sZv0[NZ];                // ray 0's fine z row (quirk)
  __shared__ float sR[4][256];              // per-wave logits, SINGLE buffer
  __shared__ __align__(16) float2 sAB[4][H];// per-wave {a,b} for layer 1

  const int tid  = threadIdx.x;
  const int wv   = tid >> 6;
  const int lane = tid & 63;
  const int ray  = blockIdx.x * 4 + wv;

  if (tid < 64) {
    const int k = tid;
    sWc.W1b[k][0] = w1c[0*H + k];
    sWc.W1b[k][1] = w1c[1*H + k];
    sWc.W1b[k][2] = w1c[2*H + k];
    sWc.W1b[k][3] = b1c[k];
    sHWc[k][0] = wrc[k*3+0]; sHWc[k][1] = wrc[k*3+1];
    sHWc[k][2] = wrc[k*3+2]; sHWc[k][3] = wdc[k];
    sB2c[k] = b2c[k];
  } else if (tid < 128) {
    const int k = tid - 64;
    sWf.W1b[k][0] = w1f[0*H + k];
    sWf.W1b[k][1] = w1f[1*H + k];
    sWf.W1b[k][2] = w1f[2*H + k];
    sWf.W1b[k][3] = b1f[k];
    sHWf[k][0] = wrf[k*3+0]; sHWf[k][1] = wrf[k*3+1];
    sHWf[k][2] = wrf[k*3+2]; sHWf[k][3] = wdf[k];
    sB2f[k] = b2f_[k];
  }
  if (tid < NZ) sZv0[tid] = gz0[tid];       // z0 row from kernel 1
  __syncthreads();

  float* R = sR[wv];
  float2* ABw = &sAB[wv][0];

  // ---- coarse pass (own ray only) ----
  {
    MfmaW Mc;
    load_mfma_weights(lane, w2c, brc, bdc, Mc);
    coarse_pass(ray, lane, origins, dirs, nearp, farp, bkgd,
                sWc, Mc, sHWc, sB2c, R, ABw,
                sT[wv], sBins[wv], sCdf[wv], sZs[wv], sZv[wv], true, out);
  }

  // ---- fine pass: 3 batches of 64 samples, rendering fused per-batch ----
  MfmaW Mf;
  load_mfma_weights(lane, w2f, brf, bdf, Mf);

  const float ox = origins[ray*3+0], oy = origins[ray*3+1], oz = origins[ray*3+2];
  const float dx = dirs[ray*3+0],    dy = dirs[ray*3+1],    dz = dirs[ray*3+2];
  const float dnorm = sqrtf(dx*dx + dy*dy + dz*dz);

  {
    const float4 wvv = *(const float4*)(&sWf.W1b[lane][0]);
    const float a = fmaf(ox, wvv.x, fmaf(oy, wvv.y, fmaf(oz, wvv.z, wvv.w)));
    const float b = fmaf(dx, wvv.x, fmaf(dy, wvv.y, dz * wvv.z));
    ABw[lane] = (float2){a, b};
  }
  __builtin_amdgcn_wave_barrier();

  float aw = 0.f, awz = 0.f, ac0 = 0.f, ac1 = 0.f, ac2 = 0.f, awz0 = 0.f;
  float offset = 0.f;
#pragma unroll 1
  for (int s = 0; s < 3; ++s) {
    mlp_mfma_batch(lane, ABw, &sZv[wv][64*s], Mf, sHWf, sB2f, R);
    const int i = lane + 64*s;
    const float4 rr = *(const float4*)(&R[lane*4]);
    const float dens = fmaxf(rr.w, 0.f);
    const float zcv = sZv[wv][i];
    const float znv = (i < NZ-1) ? sZv[wv][i+1] : 0.f;
    const float td  = (i == NZ-1) ? 1e10f : fmaxf(znv - zcv, 0.f);
    const float ddv = fminf(dens * (td * dnorm), 1e4f);
    const float incl  = wave_incl_scan(ddv, lane);
    const float exclv = offset + incl - ddv;
    offset += __shfl(incl, 63);
    const float wgt = (1.f - __expf(-ddv)) * __expf(-exclv);  // output-only: fast
    aw   += wgt;
    awz  += wgt * zcv;
    ac0  += wgt * fsig(rr.x);
    ac1  += wgt * fsig(rr.y);
    ac2  += wgt * fsig(rr.z);
    awz0 += wgt * sZv0[i];
    __builtin_amdgcn_wave_barrier();   // reads of R done before next overwrite
  }
  aw  = wave_sum(aw);  awz = wave_sum(awz); ac0 = wave_sum(ac0);
  ac1 = wave_sum(ac1); ac2 = wave_sum(ac2); awz0 = wave_sum(awz0);

  if (lane == 0) {
    const float bk0 = bkgd[0], bk1 = bkgd[1], bk2 = bkgd[2];
    const float o0x = origins[0], o0y = origins[1], o0z = origins[2];
    const float d0x = dirs[0],    d0y = dirs[1],    d0z = dirs[2];
    const float oma = 1.f - aw;
    float* o = out + (size_t)ray * 16 + 8;
    o[0] = ac0 + bk0 * oma;
    o[1] = ac1 + bk1 * oma;
    o[2] = ac2 + bk2 * oma;
    o[3] = awz;
    o[4] = aw;
    o[5] = aw * o0x + awz0 * d0x;
    o[6] = aw * o0y + awz0 * d0y;
    o[7] = aw * o0z + awz0 * d0z;
  }
}

extern "C" void kernel_launch(void* const* d_in, const int* in_sizes, int n_in,
                              void* d_out, int out_size, void* d_ws, size_t ws_size,
                              hipStream_t stream) {
  const float* origins = (const float*)d_in[0];
  const float* dirs    = (const float*)d_in[1];
  const float* nearp   = (const float*)d_in[2];
  const float* farp    = (const float*)d_in[3];
  const float* bkgd    = (const float*)d_in[4];
  const float* w1c  = (const float*)d_in[5];
  const float* b1c  = (const float*)d_in[6];
  const float* w2c  = (const float*)d_in[7];
  const float* b2c  = (const float*)d_in[8];
  const float* wrc  = (const float*)d_in[9];
  const float* brc  = (const float*)d_in[10];
  const float* wdc  = (const float*)d_in[11];
  const float* bdc  = (const float*)d_in[12];
  const float* w1f  = (const float*)d_in[13];
  const float* b1f  = (const float*)d_in[14];
  const float* w2f  = (const float*)d_in[15];
  const float* b2f_ = (const float*)d_in[16];
  const float* wrf  = (const float*)d_in[17];
  const float* brf  = (const float*)d_in[18];
  const float* wdf  = (const float*)d_in[19];
  const float* bdf  = (const float*)d_in[20];

  float* gz0 = (float*)d_ws;   // 192 floats = 768 B of scratch (proven size)

  nerf_z0_kernel<<<1, 256, 0, stream>>>(
      origins, dirs, nearp, farp,
      w1c, b1c, w2c, b2c, wrc, brc, wdc, bdc, gz0);

  nerf_fused_kernel<<<NRAYS/4, 256, 0, stream>>>(
      origins, dirs, nearp, farp, bkgd,
      w1c, b1c, w2c, b2c, wrc, brc, wdc, bdc,
      w1f, b1f, w2f, b2f_, wrf, brf, wdf, bdf,
      gz0, (float*)d_out);
}

// Round 11
// 290.372 us; speedup vs baseline: 1.4335x; 1.0242x over previous
//
#include <hip/hip_runtime.h>
#include <math.h>

#define NRAYS 16384
#define NC    64
#define NF    128
#define NZ    192   // NC + NF
#define H     64

typedef __attribute__((ext_vector_type(8))) short bf16x8;  // 8 bf16 (4 VGPRs)
typedef __attribute__((ext_vector_type(4))) float f32x4;   // MFMA C/D
typedef __attribute__((ext_vector_type(4))) int   i32x4;

// R18/R20 lesson (twice-confirmed): ANY f32x2 packed-math use costs +8 VGPR
// (even-pair alignment fragments allocation) -> occupancy halves at the 128
// cliff -> net loss. No f32x2 anywhere in this kernel.
// R13/R22 lesson (twice-failed, mechanism unidentified): pre-split w2
// fragments routed через d_ws between kernels arrive corrupted. d_ws is used
// ONLY for the 768 B gz0 row (proven). Fragment dedup is done in-block via
// LDS instead (this round).

// One-instruction pack: result = (a & 0xFFFF0000) | (b >> 16).
// v_perm_b32 byte-select; bit-identical to the 3-op form (verified R20/R21).
__device__ __forceinline__ int pack_hi16(unsigned a, unsigned b) {
  return (int)__builtin_amdgcn_perm(a, b, 0x07060302u);
}

__device__ __forceinline__ float wave_incl_scan(float v, int lane) {
#pragma unroll
  for (int off = 1; off < 64; off <<= 1) {
    float n = __shfl_up(v, off);
    v = (lane >= off) ? v + n : v;
  }
  return v;
}

__device__ __forceinline__ float wave_incl_max_scan(float v, int lane) {
#pragma unroll
  for (int off = 1; off < 64; off <<= 1) {
    float n = __shfl_up(v, off);
    v = (lane >= off) ? fmaxf(v, n) : v;
  }
  return v;
}

__device__ __forceinline__ float wave_sum(float v) {
#pragma unroll
  for (int off = 32; off > 0; off >>= 1) v += __shfl_xor(v, off);
  return v;
}

// fp32 -> bf16 hi + bf16 lo (truncation split; 3-term MFMA has rel err ~2^-15).
__device__ __forceinline__ void split_bf16(float f, short& hi, short& lo) {
  unsigned u = __float_as_uint(f);
  hi = (short)(u >> 16);
  float rem = f - __uint_as_float(u & 0xFFFF0000u);   // exact
  lo = (short)(__float_as_uint(rem) >> 16);
}

// Fast sigmoid: OUTPUT-ONLY paths (never feeds the coarse pdf->cdf->sampling
// chain, which must stay bit-stable: bin flips cost O(0.03) absmax).
__device__ __forceinline__ float fsig(float x) {
  return __builtin_amdgcn_rcpf(1.f + __expf(-x));
}

// Layer-1 weights in LDS — read per-batch via a/b precompute.
struct __align__(16) WLds {
  float W1b[H][4];   // {w1[0][k], w1[1][k], w1[2][k], b1[k]}
};

// Register-resident w2 fragments (hi/lo split) + head bias.
struct MfmaW {
  bf16x8 Bhi[2][4], Blo[2][4];  // w2 [kt][jt]
  float  hbown;                 // head bias for this lane's c = n16&3
};

// Full per-lane fragment build from raw fp32 w2 — used by kernel 1 only.
__device__ __forceinline__ void load_mfma_weights(
    int lane,
    const float* __restrict__ w2,
    const float* __restrict__ br, const float* __restrict__ bd,
    MfmaW& M)
{
  const int quad = lane >> 4, n16 = lane & 15;
#pragma unroll
  for (int kt = 0; kt < 2; ++kt) {
#pragma unroll
    for (int jt = 0; jt < 4; ++jt) {
#pragma unroll
      for (int j = 0; j < 8; ++j) {
        const int k = kt*32 + quad*8 + j;
        short hi, lo;
        split_bf16(w2[k*H + jt*16 + n16], hi, lo);
        M.Bhi[kt][jt][j] = hi; M.Blo[kt][jt][j] = lo;
      }
    }
  }
  const int c = n16 & 3;
  M.hbown = (c == 0) ? br[0] : (c == 1) ? br[1] : (c == 2) ? br[2] : bd[0];
}

// Load this lane's fragments from an LDS staging buffer (bit-identical to
// load_mfma_weights: same split math was applied by the builder thread with
// the SAME lane index; LDS roundtrip is exact).
__device__ __forceinline__ void load_frags_lds(
    int lane, const i32x4* src,
    const float* __restrict__ br, const float* __restrict__ bd, MfmaW& M)
{
  union { i32x4 i; bf16x8 h; } u;
#pragma unroll
  for (int kt = 0; kt < 2; ++kt)
#pragma unroll
    for (int jt = 0; jt < 4; ++jt) {
      const int s = kt*4 + jt;
      u.i = src[s*64 + lane];     M.Bhi[kt][jt] = u.h;
      u.i = src[(8+s)*64 + lane]; M.Blo[kt][jt] = u.h;
    }
  const int c = lane & 3;
  M.hbown = (c == 0) ? br[0] : (c == 1) ? br[1] : (c == 2) ? br[2] : bd[0];
}

// ONE mt sub-batch (16 samples) — used by kernel 1's 4-wave MLP (mt = wave id).
__device__ __forceinline__ void mlp_mfma_batch_one(
    int mt, int lane, const float2* __restrict__ AB,
    const float* __restrict__ zsrc, const MfmaW& M,
    const float (*__restrict__ sHW)[4], const float* __restrict__ sB2,
    float* __restrict__ R)
{
  const int quad = lane >> 4, n16 = lane & 15;
  const float z = zsrc[mt*16 + n16];
  f32x4 C[4];
#pragma unroll
  for (int jt = 0; jt < 4; ++jt) {
    const float b2v = sB2[jt*16 + n16];
    C[jt] = (f32x4){b2v, b2v, b2v, b2v};
  }
#pragma unroll
  for (int kt = 0; kt < 2; ++kt) {
    const float4* abp = (const float4*)(AB + kt*32 + quad*8);
    i32x4 hip, lop;
#pragma unroll
    for (int j2 = 0; j2 < 4; ++j2) {
      const float4 p = abp[j2];                 // {a0,b0,a1,b1}
      const float h0 = fmaxf(fmaf(z, p.y, p.x), 0.f);
      const float h1 = fmaxf(fmaf(z, p.w, p.z), 0.f);
      const unsigned u0 = __float_as_uint(h0), u1 = __float_as_uint(h1);
      hip[j2] = pack_hi16(u1, u0);
      const float r0 = h0 - __uint_as_float(u0 & 0xFFFF0000u);
      const float r1 = h1 - __uint_as_float(u1 & 0xFFFF0000u);
      lop[j2] = pack_hi16(__float_as_uint(r1), __float_as_uint(r0));
    }
    union { i32x4 i; bf16x8 h; } uh, ul;
    uh.i = hip; ul.i = lop;
#pragma unroll
    for (int jt = 0; jt < 4; ++jt) {
      C[jt] = __builtin_amdgcn_mfma_f32_16x16x32_bf16(uh.h, M.Bhi[kt][jt], C[jt], 0, 0, 0);
      C[jt] = __builtin_amdgcn_mfma_f32_16x16x32_bf16(ul.h, M.Bhi[kt][jt], C[jt], 0, 0, 0);
      C[jt] = __builtin_amdgcn_mfma_f32_16x16x32_bf16(uh.h, M.Blo[kt][jt], C[jt], 0, 0, 0);
    }
  }
  float P[16];
#pragma unroll
  for (int i = 0; i < 16; ++i) P[i] = 0.f;
#pragma unroll
  for (int jt = 0; jt < 4; ++jt) {
    const float4 hwv = *(const float4*)(&sHW[jt*16 + n16][0]);
#pragma unroll
    for (int r = 0; r < 4; ++r) {
      const float h2v = fmaxf(C[jt][r], 0.f);
      P[r*4 + 0] = fmaf(h2v, hwv.x, P[r*4 + 0]);
      P[r*4 + 1] = fmaf(h2v, hwv.y, P[r*4 + 1]);
      P[r*4 + 2] = fmaf(h2v, hwv.z, P[r*4 + 2]);
      P[r*4 + 3] = fmaf(h2v, hwv.w, P[r*4 + 3]);
    }
  }
  const bool b0 = (n16 & 1), b1 = (n16 & 2), b2_ = (n16 & 4), b3 = (n16 & 8);
  float Q[8];
#pragma unroll
  for (int s = 0; s < 8; ++s) {
    const float give = b0 ? P[2*s] : P[2*s+1];
    const float keep = b0 ? P[2*s+1] : P[2*s];
    Q[s] = keep + __shfl_xor(give, 1);
  }
  float U[4];
#pragma unroll
  for (int t = 0; t < 4; ++t) {
    const float give = b1 ? Q[2*t] : Q[2*t+1];
    const float keep = b1 ? Q[2*t+1] : Q[2*t];
    U[t] = keep + __shfl_xor(give, 2);
  }
  float V[2];
#pragma unroll
  for (int u = 0; u < 2; ++u) {
    const float give = b2_ ? U[2*u] : U[2*u+1];
    const float keep = b2_ ? U[2*u+1] : U[2*u];
    V[u] = keep + __shfl_xor(give, 4);
  }
  {
    const float give = b3 ? V[0] : V[1];
    const float keep = b3 ? V[1] : V[0];
    const float total = keep + __shfl_xor(give, 8);
    R[mt*64 + lane] = total + M.hbown;   // coalesced: addr = sample*4 + c
  }
}

// One 64-sample MLP batch (monolithic) — used by kernel 2.
__device__ __forceinline__ void mlp_mfma_batch(
    int lane, const float2* __restrict__ AB,
    const float* __restrict__ zsrc, const MfmaW& M,
    const float (*__restrict__ sHW)[4], const float* __restrict__ sB2,
    float* __restrict__ R)
{
  const int quad = lane >> 4, n16 = lane & 15;
  float b2q[4];
#pragma unroll
  for (int jt = 0; jt < 4; ++jt) b2q[jt] = sB2[jt*16 + n16];
#pragma unroll 1   // rolled: prevents register blow-up (R5/R6 lesson)
  for (int mt = 0; mt < 4; ++mt) {
    const float z = zsrc[mt*16 + n16];
    f32x4 C[4];
#pragma unroll
    for (int jt = 0; jt < 4; ++jt)
      C[jt] = (f32x4){b2q[jt], b2q[jt], b2q[jt], b2q[jt]};
#pragma unroll
    for (int kt = 0; kt < 2; ++kt) {
      const float4* abp = (const float4*)(AB + kt*32 + quad*8);
      i32x4 hip, lop;
#pragma unroll
      for (int j2 = 0; j2 < 4; ++j2) {
        const float4 p = abp[j2];                 // {a0,b0,a1,b1}
        const float h0 = fmaxf(fmaf(z, p.y, p.x), 0.f);
        const float h1 = fmaxf(fmaf(z, p.w, p.z), 0.f);
        const unsigned u0 = __float_as_uint(h0), u1 = __float_as_uint(h1);
        hip[j2] = pack_hi16(u1, u0);
        const float r0 = h0 - __uint_as_float(u0 & 0xFFFF0000u);
        const float r1 = h1 - __uint_as_float(u1 & 0xFFFF0000u);
        lop[j2] = pack_hi16(__float_as_uint(r1), __float_as_uint(r0));
      }
      union { i32x4 i; bf16x8 h; } uh, ul;
      uh.i = hip; ul.i = lop;
#pragma unroll
      for (int jt = 0; jt < 4; ++jt) {
        C[jt] = __builtin_amdgcn_mfma_f32_16x16x32_bf16(uh.h, M.Bhi[kt][jt], C[jt], 0, 0, 0);
        C[jt] = __builtin_amdgcn_mfma_f32_16x16x32_bf16(ul.h, M.Bhi[kt][jt], C[jt], 0, 0, 0);
        C[jt] = __builtin_amdgcn_mfma_f32_16x16x32_bf16(uh.h, M.Blo[kt][jt], C[jt], 0, 0, 0);
      }
    }
    float P[16];
#pragma unroll
    for (int i = 0; i < 16; ++i) P[i] = 0.f;
#pragma unroll
    for (int jt = 0; jt < 4; ++jt) {
      const float4 hwv = *(const float4*)(&sHW[jt*16 + n16][0]);
#pragma unroll
      for (int r = 0; r < 4; ++r) {
        const float h2v = fmaxf(C[jt][r], 0.f);
        P[r*4 + 0] = fmaf(h2v, hwv.x, P[r*4 + 0]);
        P[r*4 + 1] = fmaf(h2v, hwv.y, P[r*4 + 1]);
        P[r*4 + 2] = fmaf(h2v, hwv.z, P[r*4 + 2]);
        P[r*4 + 3] = fmaf(h2v, hwv.w, P[r*4 + 3]);
      }
    }
    const bool b0 = (n16 & 1), b1 = (n16 & 2), b2_ = (n16 & 4), b3 = (n16 & 8);
    float Q[8];
#pragma unroll
    for (int s = 0; s < 8; ++s) {
      const float give = b0 ? P[2*s] : P[2*s+1];
      const float keep = b0 ? P[2*s+1] : P[2*s];
      Q[s] = keep + __shfl_xor(give, 1);
    }
    float U[4];
#pragma unroll
    for (int t = 0; t < 4; ++t) {
      const float give = b1 ? Q[2*t] : Q[2*t+1];
      const float keep = b1 ? Q[2*t+1] : Q[2*t];
      U[t] = keep + __shfl_xor(give, 2);
    }
    float V[2];
#pragma unroll
    for (int u = 0; u < 2; ++u) {
      const float give = b2_ ? U[2*u] : U[2*u+1];
      const float keep = b2_ ? U[2*u+1] : U[2*u];
      V[u] = keep + __shfl_xor(give, 4);
    }
    {
      const float give = b3 ? V[0] : V[1];
      const float keep = b3 ? V[1] : V[0];
      const float total = keep + __shfl_xor(give, 8);
      R[mt*64 + lane] = total + M.hbown;   // coalesced: addr = sample*4 + c
    }
  }
  __builtin_amdgcn_wave_barrier();     // R complete before readback
}

// Coarse pass for one ray, ONE wave, wave-private LDS scratch.
// NOTE: alpha/trans keep ACCURATE expf — they feed the pdf->cdf->inverse-CDF
// chain; perturbing them can flip binary-search bins (absmax blowup).
__device__ __forceinline__ void coarse_pass(
    int ray, int lane,
    const float* __restrict__ origins, const float* __restrict__ dirs,
    const float* __restrict__ nearp, const float* __restrict__ farp,
    const float* __restrict__ bkgd,
    const WLds& W, const MfmaW& M,
    const float (*__restrict__ sHW)[4], const float* __restrict__ sB2,
    float* __restrict__ R, float2* __restrict__ sAB,
    float* __restrict__ sT, float* __restrict__ sBins,
    float* __restrict__ sCdf, float* __restrict__ sZs,
    float* __restrict__ zdst, bool emit, float* __restrict__ out)
{
  const float nearv = nearp[ray];
  const float farv  = farp[ray];
  const float ox = origins[ray*3+0], oy = origins[ray*3+1], oz = origins[ray*3+2];
  const float dx = dirs[ray*3+0],    dy = dirs[ray*3+1],    dz = dirs[ray*3+2];

  {
    const float4 wv = *(const float4*)(&W.W1b[lane][0]);
    const float a = fmaf(ox, wv.x, fmaf(oy, wv.y, fmaf(oz, wv.z, wv.w)));
    const float b = fmaf(dx, wv.x, fmaf(dy, wv.y, dz * wv.z));
    sAB[lane] = (float2){a, b};
  }

  const float u_i  = (float)lane / 63.0f;
  const float u_n  = (float)(lane + 1) / 63.0f;
  const float tv    = nearv * (1.f - u_i) + farv * u_i;
  const float tnext = nearv * (1.f - u_n) + farv * u_n;

  sT[lane] = tv;
  if (lane < NC-1) sBins[lane] = 0.5f * (tv + tnext);
  zdst[lane] = 0.f; zdst[lane+64] = 0.f; zdst[lane+128] = 0.f;
  __builtin_amdgcn_wave_barrier();     // sT + sAB ready for the batch

  mlp_mfma_batch(lane, sAB, sT, M, sHW, sB2, R);
  const float4 rr = *(const float4*)(&R[lane*4]);
  const float rgb0 = fsig(rr.x), rgb1 = fsig(rr.y), rgb2 = fsig(rr.z);
  const float dens = fmaxf(rr.w, 0.f);

  const float dnorm = sqrtf(dx*dx + dy*dy + dz*dz);
  const float tdist = (lane == NC-1) ? 1e10f : (tnext - tv);
  const float dd    = fminf(dens * (tdist * dnorm), 1e4f);
  const float incl  = wave_incl_scan(dd, lane);
  const float excl  = incl - dd;
  const float alpha = 1.f - expf(-dd);     // pdf-critical: accurate
  const float trans = expf(-excl);         // pdf-critical: accurate
  const float w     = alpha * trans;

  if (emit) {
    const float near0 = nearp[0], far0 = farp[0];
    const float t0v   = near0 * (1.f - u_i) + far0 * u_i;
    const float s_w   = wave_sum(w);
    const float s_wt  = wave_sum(w * tv);
    const float s_c0  = wave_sum(w * rgb0);
    const float s_c1  = wave_sum(w * rgb1);
    const float s_c2  = wave_sum(w * rgb2);
    const float s_wt0 = wave_sum(w * t0v);
    if (lane == 0) {
      const float bk0 = bkgd[0], bk1 = bkgd[1], bk2 = bkgd[2];
      const float o0x = origins[0], o0y = origins[1], o0z = origins[2];
      const float d0x = dirs[0],    d0y = dirs[1],    d0z = dirs[2];
      const float oma = 1.f - s_w;
      float* o = out + (size_t)ray * 16;
      o[0] = s_c0 + bk0 * oma;
      o[1] = s_c1 + bk1 * oma;
      o[2] = s_c2 + bk2 * oma;
      o[3] = s_wt;
      o[4] = s_w;
      o[5] = s_w * o0x + s_wt0 * d0x;
      o[6] = s_w * o0y + s_wt0 * d0y;
      o[7] = s_w * o0z + s_wt0 * d0z;
    }
  }

  // ---- PDF -> CDF (62 weights = w[1..62]) ----
  const float wnext = __shfl_down(w, 1);
  const float pw = (lane < NC-2) ? wnext : 0.f;
  const float ws_sum = wave_sum(pw);
  const float pad = fmaxf(1e-5f - ws_sum, 0.f);
  const float wsp = ws_sum + pad;
  const float pdf = (lane < NC-2) ? (pw + pad * (1.f/62.f)) / wsp : 0.f;
  float ip  = wave_incl_scan(pdf, lane);
  ip = wave_incl_max_scan(ip, lane);       // exact monotone
  if (lane < 61)  sCdf[lane+1] = fminf(ip, 1.f);
  if (lane == 61) sCdf[0]  = 0.f;
  if (lane == 62) sCdf[62] = 1.f;
  __builtin_amdgcn_wave_barrier();

  // ---- inverse-CDF: 128 samples, 2 per lane ----
  const float ustep = (1.0f - 1.1920929e-07f) / 127.0f;
#pragma unroll
  for (int r = 0; r < 2; ++r) {
    const int k = lane + 64*r;
    const float u = k * ustep;
    int lo = 0, hi = 61;
    while (lo < hi) {
      const int mid = (lo + hi + 1) >> 1;
      if (sCdf[mid] <= u) lo = mid; else hi = mid - 1;
    }
    const int J = lo;
    const float cg0 = sCdf[J],  cg1 = sCdf[J+1];
    const float bg0 = sBins[J], bg1 = sBins[J+1];
    const float denom = cg1 - cg0;
    const float num   = u - cg0;
    float tt;
    if (denom > 0.f) tt = fminf(fmaxf(num / denom, 0.f), 1.f);
    else             tt = (num > 0.f) ? 1.f : 0.f;
    sZs[k] = fmaf(tt, bg1 - bg0, bg0);
  }
  __builtin_amdgcn_wave_barrier();

  // ---- stable rank merge of sorted t (64) and z (128) into zdst (192) ----
  {
    int l = 0, r = NF;
    while (l < r) { const int m = (l + r) >> 1; if (sZs[m] < tv) l = m + 1; else r = m; }
    zdst[lane + l] = tv;
  }
#pragma unroll
  for (int r2 = 0; r2 < 2; ++r2) {
    const int k = lane + 64*r2;
    const float z = sZs[k];
    int l = 0, r = NC;
    while (l < r) { const int m = (l + r) >> 1; if (sT[m] <= z) l = m + 1; else r = m; }
    zdst[k + l] = z;
  }
  __builtin_amdgcn_wave_barrier();
}

// -------- Kernel 1: ONE block, 4 waves (R21-verbatim, verified). MLP is
// 4-wave (wave wv computes mt = wv); the serial tail runs on wave 0. --------
__global__ __launch_bounds__(256) void nerf_z0_kernel(
    const float* __restrict__ origins, const float* __restrict__ dirs,
    const float* __restrict__ nearp, const float* __restrict__ farp,
    const float* __restrict__ w1c, const float* __restrict__ b1c,
    const float* __restrict__ w2c, const float* __restrict__ b2c,
    const float* __restrict__ wrc, const float* __restrict__ brc,
    const float* __restrict__ wdc, const float* __restrict__ bdc,
    float* __restrict__ gz0)
{
  __shared__ WLds sW;
  __shared__ float sHW[H][4];
  __shared__ float sB2[H];
  __shared__ float sT[NC], sBins[NC], sCdf[NC], sZs[NF], sZv0[NZ];
  __shared__ float sR[256];
  __shared__ __align__(16) float2 sAB[H];

  const int tid  = threadIdx.x;
  const int wv   = tid >> 6;
  const int lane = tid & 63;

  if (tid < 64) {
    const int k = tid;
    sW.W1b[k][0] = w1c[0*H + k];
    sW.W1b[k][1] = w1c[1*H + k];
    sW.W1b[k][2] = w1c[2*H + k];
    sW.W1b[k][3] = b1c[k];
    sHW[k][0] = wrc[k*3 + 0];
    sHW[k][1] = wrc[k*3 + 1];
    sHW[k][2] = wrc[k*3 + 2];
    sHW[k][3] = wdc[k];
    sB2[k]    = b2c[k];
  }

  MfmaW Mc;                         // every wave needs the fragments
  load_mfma_weights(lane, w2c, brc, bdc, Mc);
  __syncthreads();                  // #1: tables visible to all waves

  const float nearv = nearp[0];
  const float farv  = farp[0];

  // ---- geometry (wave 0; identical formulas to coarse_pass) ----
  if (wv == 0) {
    const float ox = origins[0], oy = origins[1], oz = origins[2];
    const float dx = dirs[0],    dy = dirs[1],    dz = dirs[2];
    const float4 wvv = *(const float4*)(&sW.W1b[lane][0]);
    const float a = fmaf(ox, wvv.x, fmaf(oy, wvv.y, fmaf(oz, wvv.z, wvv.w)));
    const float b = fmaf(dx, wvv.x, fmaf(dy, wvv.y, dz * wvv.z));
    sAB[lane] = (float2){a, b};

    const float u_i  = (float)lane / 63.0f;
    const float u_n  = (float)(lane + 1) / 63.0f;
    const float tv    = nearv * (1.f - u_i) + farv * u_i;
    const float tnext = nearv * (1.f - u_n) + farv * u_n;
    sT[lane] = tv;
    if (lane < NC-1) sBins[lane] = 0.5f * (tv + tnext);
    sZv0[lane] = 0.f; sZv0[lane+64] = 0.f; sZv0[lane+128] = 0.f;
  }
  __syncthreads();                  // #2: sAB/sT ready for all waves

  // ---- 4-wave MLP, wave wv does mt = wv ----
  mlp_mfma_batch_one(wv, lane, sAB, sT, Mc, sHW, sB2, sR);
  __syncthreads();                  // #3: sR complete

  // ---- serial tail: wave 0 only (verified R15 tail, emit=false) ----
  if (wv == 0) {
    const float dx = dirs[0], dy = dirs[1], dz = dirs[2];
    const float u_i  = (float)lane / 63.0f;
    const float u_n  = (float)(lane + 1) / 63.0f;
    const float tv    = nearv * (1.f - u_i) + farv * u_i;
    const float tnext = nearv * (1.f - u_n) + farv * u_n;

    const float4 rr = *(const float4*)(&sR[lane*4]);
    const float dens = fmaxf(rr.w, 0.f);

    const float dnorm = sqrtf(dx*dx + dy*dy + dz*dz);
    const float tdist = (lane == NC-1) ? 1e10f : (tnext - tv);
    const float dd    = fminf(dens * (tdist * dnorm), 1e4f);
    const float incl  = wave_incl_scan(dd, lane);
    const float excl  = incl - dd;
    const float alpha = 1.f - expf(-dd);     // pdf-critical: accurate
    const float trans = expf(-excl);         // pdf-critical: accurate
    const float w     = alpha * trans;

    const float wnext = __shfl_down(w, 1);
    const float pw = (lane < NC-2) ? wnext : 0.f;
    const float ws_sum = wave_sum(pw);
    const float pad = fmaxf(1e-5f - ws_sum, 0.f);
    const float wsp = ws_sum + pad;
    const float pdf = (lane < NC-2) ? (pw + pad * (1.f/62.f)) / wsp : 0.f;
    float ip  = wave_incl_scan(pdf, lane);
    ip = wave_incl_max_scan(ip, lane);       // exact monotone
    if (lane < 61)  sCdf[lane+1] = fminf(ip, 1.f);
    if (lane == 61) sCdf[0]  = 0.f;
    if (lane == 62) sCdf[62] = 1.f;
    __builtin_amdgcn_wave_barrier();

    const float ustep = (1.0f - 1.1920929e-07f) / 127.0f;
#pragma unroll
    for (int r = 0; r < 2; ++r) {
      const int k = lane + 64*r;
      const float u = k * ustep;
      int lo = 0, hi = 61;
      while (lo < hi) {
        const int mid = (lo + hi + 1) >> 1;
        if (sCdf[mid] <= u) lo = mid; else hi = mid - 1;
      }
      const int J = lo;
      const float cg0 = sCdf[J],  cg1 = sCdf[J+1];
      const float bg0 = sBins[J], bg1 = sBins[J+1];
      const float denom = cg1 - cg0;
      const float num   = u - cg0;
      float tt;
      if (denom > 0.f) tt = fminf(fmaxf(num / denom, 0.f), 1.f);
      else             tt = (num > 0.f) ? 1.f : 0.f;
      sZs[k] = fmaf(tt, bg1 - bg0, bg0);
    }
    __builtin_amdgcn_wave_barrier();

    {
      int l = 0, r = NF;
      while (l < r) { const int m = (l + r) >> 1; if (sZs[m] < tv) l = m + 1; else r = m; }
      sZv0[lane + l] = tv;
    }
#pragma unroll
    for (int r2 = 0; r2 < 2; ++r2) {
      const int k = lane + 64*r2;
      const float z = sZs[k];
      int l = 0, r = NC;
      while (l < r) { const int m = (l + r) >> 1; if (sT[m] <= z) l = m + 1; else r = m; }
      sZv0[k + l] = z;
    }
    __builtin_amdgcn_wave_barrier();

#pragma unroll
    for (int s = 0; s < 3; ++s) gz0[lane + 64*s] = sZv0[lane + 64*s];
  }
}

// -------- Kernel 2: 4 waves = 4 rays per block; SINGLE fine R buffer;
// NEW: block-cooperative fragment build. All 4 waves' fragments are
// identical functions of lane, so build each net's 16 fragment slots ONCE
// per block (wave wv builds slots {2wv,2wv+1} of both nets into LDS), then
// every wave ds_reads its registers. 4x less build work; bit-identical. ----
__global__ __launch_bounds__(256) void nerf_fused_kernel(
    const float* __restrict__ origins, const float* __restrict__ dirs,
    const float* __restrict__ nearp, const float* __restrict__ farp,
    const float* __restrict__ bkgd,
    const float* __restrict__ w1c, const float* __restrict__ b1c,
    const float* __restrict__ w2c, const float* __restrict__ b2c,
    const float* __restrict__ wrc, const float* __restrict__ brc,
    const float* __restrict__ wdc, const float* __restrict__ bdc,
    const float* __restrict__ w1f, const float* __restrict__ b1f,
    const float* __restrict__ w2f, const float* __restrict__ b2f_,
    const float* __restrict__ wrf, const float* __restrict__ brf,
    const float* __restrict__ wdf, const float* __restrict__ bdf,
    const float* __restrict__ gz0, float* __restrict__ out)
{
  __shared__ WLds sWc, sWf;
  __shared__ float sHWc[H][4], sHWf[H][4];
  __shared__ float sB2c[H], sB2f[H];
  __shared__ float sT[4][NC];
  __shared__ float sBins[4][NC];
  __shared__ float sCdf[4][NC];
  __shared__ float sZs[4][NF];
  __shared__ float sZv[4][NZ];
  __shared__ float sZv0[NZ];                // ray 0's fine z row (quirk)
  __shared__ float sR[4][256];              // per-wave logits, SINGLE buffer
  __shared__ __align__(16) float2 sAB[4][H];// per-wave {a,b} for layer 1
  __shared__ i32x4 sFragC[16*64];           // coarse w2 fragments (16 KB)
  __shared__ i32x4 sFragF[16*64];           // fine   w2 fragments (16 KB)

  const int tid  = threadIdx.x;
  const int wv   = tid >> 6;
  const int lane = tid & 63;
  const int ray  = blockIdx.x * 4 + wv;

  if (tid < 64) {
    const int k = tid;
    sWc.W1b[k][0] = w1c[0*H + k];
    sWc.W1b[k][1] = w1c[1*H + k];
    sWc.W1b[k][2] = w1c[2*H + k];
    sWc.W1b[k][3] = b1c[k];
    sHWc[k][0] = wrc[k*3+0]; sHWc[k][1] = wrc[k*3+1];
    sHWc[k][2] = wrc[k*3+2]; sHWc[k][3] = wdc[k];
    sB2c[k] = b2c[k];
  } else if (tid < 128) {
    const int k = tid - 64;
    sWf.W1b[k][0] = w1f[0*H + k];
    sWf.W1b[k][1] = w1f[1*H + k];
    sWf.W1b[k][2] = w1f[2*H + k];
    sWf.W1b[k][3] = b1f[k];
    sHWf[k][0] = wrf[k*3+0]; sHWf[k][1] = wrf[k*3+1];
    sHWf[k][2] = wrf[k*3+2]; sHWf[k][3] = wdf[k];
    sB2f[k] = b2f_[k];
  }
  if (tid < NZ) sZv0[tid] = gz0[tid];       // z0 row from kernel 1

  // ---- cooperative fragment build: wave wv -> slots {2wv, 2wv+1} of BOTH
  // nets. Same split/pack math as load_mfma_weights for lane L => same bits.
  {
    const int quad = lane >> 4, n16 = lane & 15;
#pragma unroll
    for (int si = 0; si < 2; ++si) {
      const int s  = 2*wv + si;           // 0..7
      const int kt = s >> 2, jt = s & 3;
      const int kbase = kt*32 + quad*8;
      i32x4 hiC, loC, hiF, loF;
#pragma unroll
      for (int w = 0; w < 4; ++w) {
        const int idx0 = (kbase + 2*w)*H + jt*16 + n16;
        const int idx1 = idx0 + H;
        {
          const float c0 = w2c[idx0], c1 = w2c[idx1];
          const unsigned u0 = __float_as_uint(c0), u1 = __float_as_uint(c1);
          hiC[w] = pack_hi16(u1, u0);
          const float r0 = c0 - __uint_as_float(u0 & 0xFFFF0000u);
          const float r1 = c1 - __uint_as_float(u1 & 0xFFFF0000u);
          loC[w] = pack_hi16(__float_as_uint(r1), __float_as_uint(r0));
        }
        {
          const float f0 = w2f[idx0], f1 = w2f[idx1];
          const unsigned u0 = __float_as_uint(f0), u1 = __float_as_uint(f1);
          hiF[w] = pack_hi16(u1, u0);
          const float r0 = f0 - __uint_as_float(u0 & 0xFFFF0000u);
          const float r1 = f1 - __uint_as_float(u1 & 0xFFFF0000u);
          loF[w] = pack_hi16(__float_as_uint(r1), __float_as_uint(r0));
        }
      }
      sFragC[s*64 + lane] = hiC;  sFragC[(8+s)*64 + lane] = loC;
      sFragF[s*64 + lane] = hiF;  sFragF[(8+s)*64 + lane] = loF;
    }
  }
  __syncthreads();   // tables + z0 row + BOTH fragment buffers ready

  float* R = sR[wv];
  float2* ABw = &sAB[wv][0];

  // ---- coarse pass (own ray only) ----
  {
    MfmaW Mc;
    load_frags_lds(lane, sFragC, brc, bdc, Mc);
    coarse_pass(ray, lane, origins, dirs, nearp, farp, bkgd,
                sWc, Mc, sHWc, sB2c, R, ABw,
                sT[wv], sBins[wv], sCdf[wv], sZs[wv], sZv[wv], true, out);
  }

  // ---- fine pass: 3 batches of 64 samples, rendering fused per-batch ----
  // (sFragF untouched since the build sync — safe to read without a new
  // block barrier; coarse_pass uses only wave-private scratch.)
  MfmaW Mf;
  load_frags_lds(lane, sFragF, brf, bdf, Mf);

  const float ox = origins[ray*3+0], oy = origins[ray*3+1], oz = origins[ray*3+2];
  const float dx = dirs[ray*3+0],    dy = dirs[ray*3+1],    dz = dirs[ray*3+2];
  const float dnorm = sqrtf(dx*dx + dy*dy + dz*dz);

  {
    const float4 wvv = *(const float4*)(&sWf.W1b[lane][0]);
    const float a = fmaf(ox, wvv.x, fmaf(oy, wvv.y, fmaf(oz, wvv.z, wvv.w)));
    const float b = fmaf(dx, wvv.x, fmaf(dy, wvv.y, dz * wvv.z));
    ABw[lane] = (float2){a, b};
  }
  __builtin_amdgcn_wave_barrier();

  float aw = 0.f, awz = 0.f, ac0 = 0.f, ac1 = 0.f, ac2 = 0.f, awz0 = 0.f;
  float offset = 0.f;
#pragma unroll 1
  for (int s = 0; s < 3; ++s) {
    mlp_mfma_batch(lane, ABw, &sZv[wv][64*s], Mf, sHWf, sB2f, R);
    const int i = lane + 64*s;
    const float4 rr = *(const float4*)(&R[lane*4]);
    const float dens = fmaxf(rr.w, 0.f);
    const float zcv = sZv[wv][i];
    const float znv = (i < NZ-1) ? sZv[wv][i+1] : 0.f;
    const float td  = (i == NZ-1) ? 1e10f : fmaxf(znv - zcv, 0.f);
    const float ddv = fminf(dens * (td * dnorm), 1e4f);
    const float incl  = wave_incl_scan(ddv, lane);
    const float exclv = offset + incl - ddv;
    offset += __shfl(incl, 63);
    const float wgt = (1.f - __expf(-ddv)) * __expf(-exclv);  // output-only: fast
    aw   += wgt;
    awz  += wgt * zcv;
    ac0  += wgt * fsig(rr.x);
    ac1  += wgt * fsig(rr.y);
    ac2  += wgt * fsig(rr.z);
    awz0 += wgt * sZv0[i];
    __builtin_amdgcn_wave_barrier();   // reads of R done before next overwrite
  }
  aw  = wave_sum(aw);  awz = wave_sum(awz); ac0 = wave_sum(ac0);
  ac1 = wave_sum(ac1); ac2 = wave_sum(ac2); awz0 = wave_sum(awz0);

  if (lane == 0) {
    const float bk0 = bkgd[0], bk1 = bkgd[1], bk2 = bkgd[2];
    const float o0x = origins[0], o0y = origins[1], o0z = origins[2];
    const float d0x = dirs[0],    d0y = dirs[1],    d0z = dirs[2];
    const float oma = 1.f - aw;
    float* o = out + (size_t)ray * 16 + 8;
    o[0] = ac0 + bk0 * oma;
    o[1] = ac1 + bk1 * oma;
    o[2] = ac2 + bk2 * oma;
    o[3] = awz;
    o[4] = aw;
    o[5] = aw * o0x + awz0 * d0x;
    o[6] = aw * o0y + awz0 * d0y;
    o[7] = aw * o0z + awz0 * d0z;
  }
}

extern "C" void kernel_launch(void* const* d_in, const int* in_sizes, int n_in,
                              void* d_out, int out_size, void* d_ws, size_t ws_size,
                              hipStream_t stream) {
  const float* origins = (const float*)d_in[0];
  const float* dirs    = (const float*)d_in[1];
  const float* nearp   = (const float*)d_in[2];
  const float* farp    = (const float*)d_in[3];
  const float* bkgd    = (const float*)d_in[4];
  const float* w1c  = (const float*)d_in[5];
  const float* b1c  = (const float*)d_in[6];
  const float* w2c  = (const float*)d_in[7];
  const float* b2c  = (const float*)d_in[8];
  const float* wrc  = (const float*)d_in[9];
  const float* brc  = (const float*)d_in[10];
  const float* wdc  = (const float*)d_in[11];
  const float* bdc  = (const float*)d_in[12];
  const float* w1f  = (const float*)d_in[13];
  const float* b1f  = (const float*)d_in[14];
  const float* w2f  = (const float*)d_in[15];
  const float* b2f_ = (const float*)d_in[16];
  const float* wrf  = (const float*)d_in[17];
  const float* brf  = (const float*)d_in[18];
  const float* wdf  = (const float*)d_in[19];
  const float* bdf  = (const float*)d_in[20];

  float* gz0 = (float*)d_ws;   // 192 floats = 768 B of scratch (proven size)

  nerf_z0_kernel<<<1, 256, 0, stream>>>(
      origins, dirs, nearp, farp,
      w1c, b1c, w2c, b2c, wrc, brc, wdc, bdc, gz0);

  nerf_fused_kernel<<<NRAYS/4, 256, 0, stream>>>(
      origins, dirs, nearp, farp, bkgd,
      w1c, b1c, w2c, b2c, wrc, brc, wdc, bdc,
      w1f, b1f, w2f, b2f_, wrf, brf, wdf, bdf,
      gz0, (float*)d_out);
}